// Round 4
// baseline (14063.101 us; speedup 1.0000x reference)
//
#include <hip/hip_runtime.h>
#include <math.h>

#define NN_  10000
#define NE_  320000
#define IND  64
#define HID  128
#define G3   384   // 3*HID
#define HC1  512   // 4 heads * 128
#define OUTD 64

typedef _Float16 h2f __attribute__((ext_vector_type(2)));
union UH4 { uint4 u; h2f h[4]; };

__device__ __forceinline__ float leakyf_(float x){ return x>0.f ? x : 0.2f*x; }
__device__ __forceinline__ float fsig_(float x){ return 1.f/(1.f+__expf(-x)); }
__device__ __forceinline__ float ftanh_(float x){ float e=__expf(2.f*x); return 1.f-2.f/(e+1.f); }

// LDS-only barrier: waits LDS ops, does NOT drain vmcnt -> global prefetch
// loads and h_out stores stay in flight across the per-step barrier.
#define BARRIER_LDS() asm volatile("s_waitcnt lgkmcnt(0)\n\ts_barrier" ::: "memory")

// ---------------------------------------------------------------------------
// Generic tiled fp32 GEMM.  C[m,n] = sum_k A[m,k] * (TB ? B[n,k] : B[k,n]) + bias[n]
// ---------------------------------------------------------------------------
template<bool TB>
__global__ __launch_bounds__(256) void gemm_k(const float* __restrict__ A,
                                              const float* __restrict__ B,
                                              const float* __restrict__ bias,
                                              float* __restrict__ C,
                                              int M, int N, int K) {
  __shared__ float As[16][65];
  __shared__ float Bs[16][65];
  const int bm = blockIdx.x * 64, bn = blockIdx.y * 64;
  const int tid = threadIdx.x;
  const int tm = (tid >> 4) << 2, tn = (tid & 15) << 2;
  float acc[4][4] = {};
  const int row = tid & 63, kq = (tid >> 6) << 2;
  for (int k0 = 0; k0 < K; k0 += 16) {
    float4 av = make_float4(0.f, 0.f, 0.f, 0.f);
    const int m = bm + row;
    if (m < M) av = *(const float4*)(A + (size_t)m * K + k0 + kq);
    As[kq + 0][row] = av.x; As[kq + 1][row] = av.y;
    As[kq + 2][row] = av.z; As[kq + 3][row] = av.w;
    if (TB) {
      float4 bv = *(const float4*)(B + (size_t)(bn + row) * K + k0 + kq);
      Bs[kq + 0][row] = bv.x; Bs[kq + 1][row] = bv.y;
      Bs[kq + 2][row] = bv.z; Bs[kq + 3][row] = bv.w;
    } else {
      const int kr = tid >> 4, nq = (tid & 15) << 2;
      float4 bv = *(const float4*)(B + (size_t)(k0 + kr) * N + bn + nq);
      Bs[kr][nq + 0] = bv.x; Bs[kr][nq + 1] = bv.y;
      Bs[kr][nq + 2] = bv.z; Bs[kr][nq + 3] = bv.w;
    }
    __syncthreads();
#pragma unroll
    for (int kk = 0; kk < 16; kk++) {
      float a[4], b[4];
#pragma unroll
      for (int i = 0; i < 4; i++) a[i] = As[kk][tm + i];
#pragma unroll
      for (int j = 0; j < 4; j++) b[j] = Bs[kk][tn + j];
#pragma unroll
      for (int i = 0; i < 4; i++)
#pragma unroll
        for (int j = 0; j < 4; j++) acc[i][j] = fmaf(a[i], b[j], acc[i][j]);
    }
    __syncthreads();
  }
#pragma unroll
  for (int i = 0; i < 4; i++) {
    const int m = bm + tm + i;
    if (m < M) {
#pragma unroll
      for (int j = 0; j < 4; j++) {
        const int n = bn + tn + j;
        float v = acc[i][j];
        if (bias) v += bias[n];
        C[(size_t)m * N + n] = v;
      }
    }
  }
}

// ---------------------------------------------------------------------------
// GRU scan.  Single block, 128 threads (2 waves).  Thread j owns the three
// gate rows (r=j, z=j+128, n=j+256) of w_hh as packed fp16 (fp32 accumulate
// via v_dot2_f32_f16).  h broadcast through LDS as packed fp16 (256 B),
// double-buffered; ONE LDS-only barrier per step (no vmcnt drain).
// gi prefetched 4 steps ahead to cover L3 gather latency.
// ---------------------------------------------------------------------------
__global__ __launch_bounds__(128, 1) void gru_scan(const float* __restrict__ gi,
                                                   const float* __restrict__ w_hh,
                                                   const float* __restrict__ b_hh,
                                                   float* __restrict__ h_out,
                                                   int T) {
  __shared__ h2f hbuf[2][HID / 2];   // packed fp16 h, double-buffered
  const int j = threadIdx.x;

  // load + convert the 3 weight rows to packed fp16 registers
  h2f wr[64], wz[64], wn[64];
#pragma unroll
  for (int i = 0; i < 32; i++) {
    float4 a = *(const float4*)(w_hh + (size_t)j * HID + i * 4);
    wr[2 * i]     = h2f{(_Float16)a.x, (_Float16)a.y};
    wr[2 * i + 1] = h2f{(_Float16)a.z, (_Float16)a.w};
  }
#pragma unroll
  for (int i = 0; i < 32; i++) {
    float4 a = *(const float4*)(w_hh + (size_t)(j + HID) * HID + i * 4);
    wz[2 * i]     = h2f{(_Float16)a.x, (_Float16)a.y};
    wz[2 * i + 1] = h2f{(_Float16)a.z, (_Float16)a.w};
  }
#pragma unroll
  for (int i = 0; i < 32; i++) {
    float4 a = *(const float4*)(w_hh + (size_t)(j + 2 * HID) * HID + i * 4);
    wn[2 * i]     = h2f{(_Float16)a.x, (_Float16)a.y};
    wn[2 * i + 1] = h2f{(_Float16)a.z, (_Float16)a.w};
  }
  const float bhr = b_hh[j];
  const float bhz = b_hh[j + HID];
  const float bhn = b_hh[j + 2 * HID];

  float hcur = 0.f;
  ((_Float16*)hbuf[0])[j] = (_Float16)0.f;
  BARRIER_LDS();

  // gi prefetch pipeline: 4 steps ahead
  float gx[4], gy[4], gz[4];
#pragma unroll
  for (int u = 0; u < 4; u++) {
    const float* gp = gi + (size_t)u * G3 + j;
    gx[u] = gp[0]; gy[u] = gp[HID]; gz[u] = gp[2 * HID];
  }

  for (int t = 0; t < T; t += 4) {
#pragma unroll
    for (int u = 0; u < 4; u++) {
      const int tc = t + u;
      // issue prefetch for tc+4 immediately (consumed 4 steps later)
      const int tp = (tc + 4 < T) ? (tc + 4) : (T - 1);
      const float* gp = gi + (size_t)tp * G3 + j;
      const float nx = gp[0], ny = gp[HID], nz = gp[2 * HID];

      const uint4* hp = (const uint4*)hbuf[u & 1];
      float ar0 = bhr, ar1 = 0.f, az0 = bhz, az1 = 0.f, an0 = bhn, an1 = 0.f;
#pragma unroll
      for (int c = 0; c < 2; c++) {        // 2 chunks of 8 uint4 (128 B each)
        uint4 hv[8];
#pragma unroll
        for (int i = 0; i < 8; i++) hv[i] = hp[c * 8 + i];
#pragma unroll
        for (int i = 0; i < 8; i++) {
          UH4 v; v.u = hv[i];
#pragma unroll
          for (int q = 0; q < 4; q++) {
            const int k = c * 32 + i * 4 + q;
            const h2f hh = v.h[q];
            if (k & 1) {
              ar1 = __builtin_amdgcn_fdot2(wr[k], hh, ar1, false);
              az1 = __builtin_amdgcn_fdot2(wz[k], hh, az1, false);
              an1 = __builtin_amdgcn_fdot2(wn[k], hh, an1, false);
            } else {
              ar0 = __builtin_amdgcn_fdot2(wr[k], hh, ar0, false);
              az0 = __builtin_amdgcn_fdot2(wz[k], hh, az0, false);
              an0 = __builtin_amdgcn_fdot2(wn[k], hh, an0, false);
            }
          }
        }
      }
      const float r = fsig_(gx[u] + ar0 + ar1);
      const float z = fsig_(gy[u] + az0 + az1);
      const float n = ftanh_(gz[u] + r * (an0 + an1));
      hcur = (1.f - z) * n + z * hcur;

      ((_Float16*)hbuf[(u & 1) ^ 1])[j] = (_Float16)hcur;
      BARRIER_LDS();
      h_out[(size_t)tc * HID + j] = hcur;
      gx[u] = nx; gy[u] = ny; gz[u] = nz;
    }
  }
}

// ---------------------------------------------------------------------------
// Attention per-node dots: a_s[n,h] = feat[n,h,:].att_src[h,:]  (same for dst)
// ---------------------------------------------------------------------------
__global__ void att_dots(const float* __restrict__ feat,
                         const float* __restrict__ att_src,
                         const float* __restrict__ att_dst,
                         float* __restrict__ a_s, float* __restrict__ a_d,
                         int heads, int C) {
  const int n = blockIdx.x;
  const int h = threadIdx.x >> 6;
  const int lane = threadIdx.x & 63;
  float ss = 0.f, dd = 0.f;
  const float* f = feat + (size_t)n * heads * C + h * C;
  for (int c = lane; c < C; c += 64) {
    const float v = f[c];
    ss = fmaf(v, att_src[h * C + c], ss);
    dd = fmaf(v, att_dst[h * C + c], dd);
  }
#pragma unroll
  for (int o = 32; o > 0; o >>= 1) {
    ss += __shfl_down(ss, o);
    dd += __shfl_down(dd, o);
  }
  if (lane == 0) { a_s[n * heads + h] = ss; a_d[n * heads + h] = dd; }
}

// ---------------------------------------------------------------------------
// CSR build (edge_index arrives as int32: ei[0..E) = src, ei[E..2E) = dst)
// ---------------------------------------------------------------------------
__global__ void edge_count(const int* __restrict__ ei, int* __restrict__ cnt, int E) {
  const int e = blockIdx.x * 256 + threadIdx.x;
  if (e < E) atomicAdd(&cnt[ei[E + e]], 1);
}

__global__ __launch_bounds__(1024) void prefix_scan(const int* __restrict__ cnt,
                                                    int* __restrict__ offs,
                                                    int* __restrict__ cursor, int N) {
  __shared__ int buf[1024];
  __shared__ int carry;
  const int tid = threadIdx.x;
  if (tid == 0) carry = 0;
  __syncthreads();
  for (int base = 0; base < N; base += 1024) {
    const int i = base + tid;
    const int v = (i < N) ? cnt[i] : 0;
    buf[tid] = v;
    __syncthreads();
    for (int d = 1; d < 1024; d <<= 1) {
      int t = 0;
      if (tid >= d) t = buf[tid - d];
      __syncthreads();
      buf[tid] += t;
      __syncthreads();
    }
    const int incl = buf[tid] + carry;
    if (i < N) { offs[i] = incl - v; cursor[i] = incl - v; }
    __syncthreads();
    if (tid == 1023) carry = incl;
    __syncthreads();
  }
  if (tid == 0) offs[N] = carry;
}

__global__ void edge_fill(const int* __restrict__ ei, int* __restrict__ cursor,
                          int* __restrict__ csr, int E) {
  const int e = blockIdx.x * 256 + threadIdx.x;
  if (e < E) {
    const int d = ei[E + e];
    const int s = ei[e];
    const int pos = atomicAdd(&cursor[d], 1);
    csr[pos] = s;
  }
}

// ---------------------------------------------------------------------------
// GAT softmax-aggregation.  One block per dst node; blockDim = heads<<cshift.
// ---------------------------------------------------------------------------
__global__ void gat_agg(const float* __restrict__ feat,
                        const float* __restrict__ a_s, const float* __restrict__ a_d,
                        const int* __restrict__ offs, const int* __restrict__ csr,
                        const float* __restrict__ bias, float* __restrict__ out,
                        int heads, int cshift, int do_relu) {
  const int n = blockIdx.x;
  const int t = threadIdx.x;
  const int HC = blockDim.x;
  const int h = t >> cshift;
  const int beg = offs[n], end = offs[n + 1];
  const float ad = a_d[n * heads + h];
  const float self_e = leakyf_(a_s[n * heads + h] + ad);
  float m = self_e;
  for (int i = beg; i < end; i++) {
    const int s = csr[i];
    m = fmaxf(m, leakyf_(a_s[s * heads + h] + ad));
  }
  float den = expf(self_e - m);
  float acc = den * feat[(size_t)n * HC + t];
  for (int i = beg; i < end; i++) {
    const int s = csr[i];
    const float wgt = expf(leakyf_(a_s[s * heads + h] + ad) - m);
    den += wgt;
    acc = fmaf(wgt, feat[(size_t)s * HC + t], acc);
  }
  float o = acc / den + bias[t];
  if (do_relu) o = fmaxf(o, 0.f);
  out[(size_t)n * HC + t] = o;
}

// ---------------------------------------------------------------------------
extern "C" void kernel_launch(void* const* d_in, const int* in_sizes, int n_in,
                              void* d_out, int out_size, void* d_ws, size_t ws_size,
                              hipStream_t stream) {
  const float* x        = (const float*)d_in[0];
  const int*   ei       = (const int*)d_in[1];   // int64 inputs arrive as int32
  const float* w_ih0    = (const float*)d_in[2];
  const float* w_hh0    = (const float*)d_in[3];
  const float* b_ih0    = (const float*)d_in[4];
  const float* b_hh0    = (const float*)d_in[5];
  const float* w_ih1    = (const float*)d_in[6];
  const float* w_hh1    = (const float*)d_in[7];
  const float* b_ih1    = (const float*)d_in[8];
  const float* b_hh1    = (const float*)d_in[9];
  const float* W1       = (const float*)d_in[10];
  const float* att_src1 = (const float*)d_in[11];
  const float* att_dst1 = (const float*)d_in[12];
  const float* bias1    = (const float*)d_in[13];
  const float* W2       = (const float*)d_in[14];
  const float* att_src2 = (const float*)d_in[15];
  const float* att_dst2 = (const float*)d_in[16];
  const float* bias2    = (const float*)d_in[17];
  float* out = (float*)d_out;

  const int N = NN_;
  const int E = in_sizes[1] / 2;

  // ---- workspace layout with overlays (peak ~50.5 MB) ----
  float* f    = (float*)d_ws;
  float* gi   = f;                         // region A
  float* h0   = f + (size_t)N * G3;        // region A (after gi)
  float* hmm1 = f;                         // = A, reused after h1 is produced
  float* h1   = f + (size_t)N * HC1;                    // B
  float* g1o  = h1 + (size_t)N * HID;                   // C
  float* hmm2 = g1o + (size_t)N * HC1;                  // D
  float* as1  = hmm2 + (size_t)N * OUTD;
  float* ad1  = as1 + (size_t)N * 4;
  float* as2  = ad1 + (size_t)N * 4;
  float* ad2  = as2 + (size_t)N;
  int* cnt    = (int*)(ad2 + (size_t)N);
  int* offs   = cnt + N;        // N+1
  int* cursor = offs + (N + 1);
  int* csr    = cursor + N;     // E

  const int mblocks = (N + 63) / 64;

  // GRU layer 0
  gemm_k<true><<<dim3(mblocks, G3 / 64), 256, 0, stream>>>(x, w_ih0, b_ih0, gi, N, G3, IND);
  gru_scan<<<1, HID, 0, stream>>>(gi, w_hh0, b_hh0, h0, N);
  // GRU layer 1
  gemm_k<true><<<dim3(mblocks, G3 / 64), 256, 0, stream>>>(h0, w_ih1, b_ih1, gi, N, G3, HID);
  gru_scan<<<1, HID, 0, stream>>>(gi, w_hh1, b_hh1, h1, N);

  // CSR by dst (shared by both GAT layers)
  hipMemsetAsync(cnt, 0, (size_t)N * sizeof(int), stream);
  edge_count<<<(E + 255) / 256, 256, 0, stream>>>(ei, cnt, E);
  prefix_scan<<<1, 1024, 0, stream>>>(cnt, offs, cursor, N);
  edge_fill<<<(E + 255) / 256, 256, 0, stream>>>(ei, cursor, csr, E);

  // GAT layer 1
  gemm_k<false><<<dim3(mblocks, HC1 / 64), 256, 0, stream>>>(h1, W1, nullptr, hmm1, N, HC1, HID);
  att_dots<<<N, 4 * 64, 0, stream>>>(hmm1, att_src1, att_dst1, as1, ad1, 4, HID);
  gat_agg<<<N, HC1, 0, stream>>>(hmm1, as1, ad1, offs, csr, bias1, g1o, 4, 7, 1);

  // GAT layer 2
  gemm_k<false><<<dim3(mblocks, OUTD / 64), 256, 0, stream>>>(g1o, W2, nullptr, hmm2, N, OUTD, HC1);
  att_dots<<<N, 1 * 64, 0, stream>>>(hmm2, att_src2, att_dst2, as2, ad2, 1, OUTD);
  gat_agg<<<N, OUTD, 0, stream>>>(hmm2, as2, ad2, offs, csr, bias2, out, 1, 6, 0);
}

// Round 5
// 11345.727 us; speedup vs baseline: 1.2395x; 1.2395x over previous
//
#include <hip/hip_runtime.h>
#include <math.h>

#define NN_  10000
#define NE_  320000
#define IND  64
#define HID  128
#define G3   384   // 3*HID
#define HC1  512   // 4 heads * 128
#define OUTD 64

typedef _Float16 h2f __attribute__((ext_vector_type(2)));
union UH4 { uint4 u; h2f h[4]; };

__device__ __forceinline__ float leakyf_(float x){ return x>0.f ? x : 0.2f*x; }
__device__ __forceinline__ float fsig_(float x){ return 1.f/(1.f+__expf(-x)); }
__device__ __forceinline__ float ftanh_(float x){ float e=__expf(2.f*x); return 1.f-2.f/(e+1.f); }

// LDS-only barrier: waits LDS ops, does NOT drain vmcnt -> global prefetch
// loads and h_out stores stay in flight across the per-step barrier.
#define BARRIER_LDS() asm volatile("s_waitcnt lgkmcnt(0)\n\ts_barrier" ::: "memory")

// ---------------------------------------------------------------------------
// Generic tiled fp32 GEMM.  C[m,n] = sum_k A[m,k] * (TB ? B[n,k] : B[k,n]) + bias[n]
// ---------------------------------------------------------------------------
template<bool TB>
__global__ __launch_bounds__(256) void gemm_k(const float* __restrict__ A,
                                              const float* __restrict__ B,
                                              const float* __restrict__ bias,
                                              float* __restrict__ C,
                                              int M, int N, int K) {
  __shared__ float As[16][65];
  __shared__ float Bs[16][65];
  const int bm = blockIdx.x * 64, bn = blockIdx.y * 64;
  const int tid = threadIdx.x;
  const int tm = (tid >> 4) << 2, tn = (tid & 15) << 2;
  float acc[4][4] = {};
  const int row = tid & 63, kq = (tid >> 6) << 2;
  for (int k0 = 0; k0 < K; k0 += 16) {
    float4 av = make_float4(0.f, 0.f, 0.f, 0.f);
    const int m = bm + row;
    if (m < M) av = *(const float4*)(A + (size_t)m * K + k0 + kq);
    As[kq + 0][row] = av.x; As[kq + 1][row] = av.y;
    As[kq + 2][row] = av.z; As[kq + 3][row] = av.w;
    if (TB) {
      float4 bv = *(const float4*)(B + (size_t)(bn + row) * K + k0 + kq);
      Bs[kq + 0][row] = bv.x; Bs[kq + 1][row] = bv.y;
      Bs[kq + 2][row] = bv.z; Bs[kq + 3][row] = bv.w;
    } else {
      const int kr = tid >> 4, nq = (tid & 15) << 2;
      float4 bv = *(const float4*)(B + (size_t)(k0 + kr) * N + bn + nq);
      Bs[kr][nq + 0] = bv.x; Bs[kr][nq + 1] = bv.y;
      Bs[kr][nq + 2] = bv.z; Bs[kr][nq + 3] = bv.w;
    }
    __syncthreads();
#pragma unroll
    for (int kk = 0; kk < 16; kk++) {
      float a[4], b[4];
#pragma unroll
      for (int i = 0; i < 4; i++) a[i] = As[kk][tm + i];
#pragma unroll
      for (int j = 0; j < 4; j++) b[j] = Bs[kk][tn + j];
#pragma unroll
      for (int i = 0; i < 4; i++)
#pragma unroll
        for (int j = 0; j < 4; j++) acc[i][j] = fmaf(a[i], b[j], acc[i][j]);
    }
    __syncthreads();
  }
#pragma unroll
  for (int i = 0; i < 4; i++) {
    const int m = bm + tm + i;
    if (m < M) {
#pragma unroll
      for (int j = 0; j < 4; j++) {
        const int n = bn + tn + j;
        float v = acc[i][j];
        if (bias) v += bias[n];
        C[(size_t)m * N + n] = v;
      }
    }
  }
}

// ---------------------------------------------------------------------------
// GRU scan.  Single block, 256 threads (4 waves, one per SIMD).
// Thread owns hidden unit j = (tid&63)|((tid>>7)<<6) and K-half
// khalf = (tid>>6)&1  (waves 0,2 = khalf 0 = "primary"; waves 1,3 = khalf 1).
// Per thread: 3 gate rows x 32 h2f fp16 weights = 96 VGPRs (no spill).
// Step: all threads dot their K-half (96 fdot2); khalf1 writes 3 partials to
// LDS; barrier; primaries combine + gate math + write fp16 h; barrier.
// gi prefetched 2 steps ahead; barriers are LDS-only (no vmcnt drain).
// ---------------------------------------------------------------------------
__global__ __launch_bounds__(256, 1) void gru_scan(const float* __restrict__ gi,
                                                   const float* __restrict__ w_hh,
                                                   const float* __restrict__ b_hh,
                                                   float* __restrict__ h_out,
                                                   int T) {
  __shared__ h2f hbuf[2][HID / 2];     // packed fp16 h, double-buffered (256 B x2)
  __shared__ float psum[3][HID];       // khalf-1 partial dots (r,z,n)
  const int tid = threadIdx.x;
  const int khalf = (tid >> 6) & 1;
  const int j = (tid & 63) | ((tid >> 7) << 6);
  const int kbase = khalf * 64;

  // load + convert this thread's half of the 3 gate rows to packed fp16
  h2f wr[32], wz[32], wn[32];
#pragma unroll
  for (int i = 0; i < 16; i++) {
    float4 a = *(const float4*)(w_hh + (size_t)j * HID + kbase + i * 4);
    wr[2 * i]     = h2f{(_Float16)a.x, (_Float16)a.y};
    wr[2 * i + 1] = h2f{(_Float16)a.z, (_Float16)a.w};
  }
#pragma unroll
  for (int i = 0; i < 16; i++) {
    float4 a = *(const float4*)(w_hh + (size_t)(j + HID) * HID + kbase + i * 4);
    wz[2 * i]     = h2f{(_Float16)a.x, (_Float16)a.y};
    wz[2 * i + 1] = h2f{(_Float16)a.z, (_Float16)a.w};
  }
#pragma unroll
  for (int i = 0; i < 16; i++) {
    float4 a = *(const float4*)(w_hh + (size_t)(j + 2 * HID) * HID + kbase + i * 4);
    wn[2 * i]     = h2f{(_Float16)a.x, (_Float16)a.y};
    wn[2 * i + 1] = h2f{(_Float16)a.z, (_Float16)a.w};
  }
  const float bhr = b_hh[j];
  const float bhz = b_hh[j + HID];
  const float bhn = b_hh[j + 2 * HID];

  float hcur = 0.f;
  if (khalf == 0) ((_Float16*)hbuf[0])[j] = (_Float16)0.f;
  BARRIER_LDS();

  // gi prefetch pipeline: 2 steps ahead (primaries only)
  float gx0, gy0, gz0, gx1, gy1, gz1;
  if (khalf == 0) {
    const float* gp = gi + j;
    gx0 = gp[0]; gy0 = gp[HID]; gz0 = gp[2 * HID];
    gp = gi + G3 + j;
    gx1 = gp[0]; gy1 = gp[HID]; gz1 = gp[2 * HID];
  }

  for (int t = 0; t < T; t += 2) {
#pragma unroll
    for (int u = 0; u < 2; u++) {
      const int tc = t + u;
      // issue gi prefetch for tc+2 early (primaries)
      float nx, ny, nz;
      if (khalf == 0) {
        const int tp = (tc + 2 < T) ? (tc + 2) : (T - 1);
        const float* gp = gi + (size_t)tp * G3 + j;
        nx = gp[0]; ny = gp[HID]; nz = gp[2 * HID];
      }

      // dot this thread's K-half: h2f[32] from byte offset kbase*2
      const uint4* hp = (const uint4*)((const _Float16*)hbuf[u] + kbase);
      float ar0 = 0.f, ar1 = 0.f, az0 = 0.f, az1 = 0.f, an0 = 0.f, an1 = 0.f;
#pragma unroll
      for (int c = 0; c < 2; c++) {          // 2 chunks of 4 uint4 (64 B each)
        uint4 hv[4];
#pragma unroll
        for (int i = 0; i < 4; i++) hv[i] = hp[c * 4 + i];
#pragma unroll
        for (int i = 0; i < 4; i++) {
          UH4 v; v.u = hv[i];
#pragma unroll
          for (int q = 0; q < 4; q++) {
            const int k = c * 16 + i * 4 + q;
            const h2f hh = v.h[q];
            if (k & 1) {
              ar1 = __builtin_amdgcn_fdot2(wr[k], hh, ar1, false);
              az1 = __builtin_amdgcn_fdot2(wz[k], hh, az1, false);
              an1 = __builtin_amdgcn_fdot2(wn[k], hh, an1, false);
            } else {
              ar0 = __builtin_amdgcn_fdot2(wr[k], hh, ar0, false);
              az0 = __builtin_amdgcn_fdot2(wz[k], hh, az0, false);
              an0 = __builtin_amdgcn_fdot2(wn[k], hh, an0, false);
            }
          }
        }
      }
      if (khalf == 1) {                      // export partials
        psum[0][j] = ar0 + ar1;
        psum[1][j] = az0 + az1;
        psum[2][j] = an0 + an1;
      }
      BARRIER_LDS();
      if (khalf == 0) {                      // combine + gates + h update
        const float r = fsig_(gx0 + bhr + ar0 + ar1 + psum[0][j]);
        const float z = fsig_(gy0 + bhz + az0 + az1 + psum[1][j]);
        const float n = ftanh_(gz0 + r * (bhn + an0 + an1 + psum[2][j]));
        hcur = (1.f - z) * n + z * hcur;
        ((_Float16*)hbuf[u ^ 1])[j] = (_Float16)hcur;
      }
      BARRIER_LDS();
      if (khalf == 0) {
        h_out[(size_t)tc * HID + j] = hcur;
        gx0 = gx1; gy0 = gy1; gz0 = gz1;     // rotate prefetch pipeline
        gx1 = nx;  gy1 = ny;  gz1 = nz;
      }
    }
  }
}

// ---------------------------------------------------------------------------
// Attention per-node dots: a_s[n,h] = feat[n,h,:].att_src[h,:]  (same for dst)
// ---------------------------------------------------------------------------
__global__ void att_dots(const float* __restrict__ feat,
                         const float* __restrict__ att_src,
                         const float* __restrict__ att_dst,
                         float* __restrict__ a_s, float* __restrict__ a_d,
                         int heads, int C) {
  const int n = blockIdx.x;
  const int h = threadIdx.x >> 6;
  const int lane = threadIdx.x & 63;
  float ss = 0.f, dd = 0.f;
  const float* f = feat + (size_t)n * heads * C + h * C;
  for (int c = lane; c < C; c += 64) {
    const float v = f[c];
    ss = fmaf(v, att_src[h * C + c], ss);
    dd = fmaf(v, att_dst[h * C + c], dd);
  }
#pragma unroll
  for (int o = 32; o > 0; o >>= 1) {
    ss += __shfl_down(ss, o);
    dd += __shfl_down(dd, o);
  }
  if (lane == 0) { a_s[n * heads + h] = ss; a_d[n * heads + h] = dd; }
}

// ---------------------------------------------------------------------------
// CSR build (edge_index arrives as int32: ei[0..E) = src, ei[E..2E) = dst)
// ---------------------------------------------------------------------------
__global__ void edge_count(const int* __restrict__ ei, int* __restrict__ cnt, int E) {
  const int e = blockIdx.x * 256 + threadIdx.x;
  if (e < E) atomicAdd(&cnt[ei[E + e]], 1);
}

__global__ __launch_bounds__(1024) void prefix_scan(const int* __restrict__ cnt,
                                                    int* __restrict__ offs,
                                                    int* __restrict__ cursor, int N) {
  __shared__ int buf[1024];
  __shared__ int carry;
  const int tid = threadIdx.x;
  if (tid == 0) carry = 0;
  __syncthreads();
  for (int base = 0; base < N; base += 1024) {
    const int i = base + tid;
    const int v = (i < N) ? cnt[i] : 0;
    buf[tid] = v;
    __syncthreads();
    for (int d = 1; d < 1024; d <<= 1) {
      int t = 0;
      if (tid >= d) t = buf[tid - d];
      __syncthreads();
      buf[tid] += t;
      __syncthreads();
    }
    const int incl = buf[tid] + carry;
    if (i < N) { offs[i] = incl - v; cursor[i] = incl - v; }
    __syncthreads();
    if (tid == 1023) carry = incl;
    __syncthreads();
  }
  if (tid == 0) offs[N] = carry;
}

__global__ void edge_fill(const int* __restrict__ ei, int* __restrict__ cursor,
                          int* __restrict__ csr, int E) {
  const int e = blockIdx.x * 256 + threadIdx.x;
  if (e < E) {
    const int d = ei[E + e];
    const int s = ei[e];
    const int pos = atomicAdd(&cursor[d], 1);
    csr[pos] = s;
  }
}

// ---------------------------------------------------------------------------
// GAT softmax-aggregation.  One block per dst node; blockDim = heads<<cshift.
// ---------------------------------------------------------------------------
__global__ void gat_agg(const float* __restrict__ feat,
                        const float* __restrict__ a_s, const float* __restrict__ a_d,
                        const int* __restrict__ offs, const int* __restrict__ csr,
                        const float* __restrict__ bias, float* __restrict__ out,
                        int heads, int cshift, int do_relu) {
  const int n = blockIdx.x;
  const int t = threadIdx.x;
  const int HC = blockDim.x;
  const int h = t >> cshift;
  const int beg = offs[n], end = offs[n + 1];
  const float ad = a_d[n * heads + h];
  const float self_e = leakyf_(a_s[n * heads + h] + ad);
  float m = self_e;
  for (int i = beg; i < end; i++) {
    const int s = csr[i];
    m = fmaxf(m, leakyf_(a_s[s * heads + h] + ad));
  }
  float den = expf(self_e - m);
  float acc = den * feat[(size_t)n * HC + t];
  for (int i = beg; i < end; i++) {
    const int s = csr[i];
    const float wgt = expf(leakyf_(a_s[s * heads + h] + ad) - m);
    den += wgt;
    acc = fmaf(wgt, feat[(size_t)s * HC + t], acc);
  }
  float o = acc / den + bias[t];
  if (do_relu) o = fmaxf(o, 0.f);
  out[(size_t)n * HC + t] = o;
}

// ---------------------------------------------------------------------------
extern "C" void kernel_launch(void* const* d_in, const int* in_sizes, int n_in,
                              void* d_out, int out_size, void* d_ws, size_t ws_size,
                              hipStream_t stream) {
  const float* x        = (const float*)d_in[0];
  const int*   ei       = (const int*)d_in[1];   // int64 inputs arrive as int32
  const float* w_ih0    = (const float*)d_in[2];
  const float* w_hh0    = (const float*)d_in[3];
  const float* b_ih0    = (const float*)d_in[4];
  const float* b_hh0    = (const float*)d_in[5];
  const float* w_ih1    = (const float*)d_in[6];
  const float* w_hh1    = (const float*)d_in[7];
  const float* b_ih1    = (const float*)d_in[8];
  const float* b_hh1    = (const float*)d_in[9];
  const float* W1       = (const float*)d_in[10];
  const float* att_src1 = (const float*)d_in[11];
  const float* att_dst1 = (const float*)d_in[12];
  const float* bias1    = (const float*)d_in[13];
  const float* W2       = (const float*)d_in[14];
  const float* att_src2 = (const float*)d_in[15];
  const float* att_dst2 = (const float*)d_in[16];
  const float* bias2    = (const float*)d_in[17];
  float* out = (float*)d_out;

  const int N = NN_;
  const int E = in_sizes[1] / 2;

  // ---- workspace layout with overlays (peak ~50.5 MB) ----
  float* f    = (float*)d_ws;
  float* gi   = f;                         // region A
  float* h0   = f + (size_t)N * G3;        // region A (after gi)
  float* hmm1 = f;                         // = A, reused after h1 is produced
  float* h1   = f + (size_t)N * HC1;                    // B
  float* g1o  = h1 + (size_t)N * HID;                   // C
  float* hmm2 = g1o + (size_t)N * HC1;                  // D
  float* as1  = hmm2 + (size_t)N * OUTD;
  float* ad1  = as1 + (size_t)N * 4;
  float* as2  = ad1 + (size_t)N * 4;
  float* ad2  = as2 + (size_t)N;
  int* cnt    = (int*)(ad2 + (size_t)N);
  int* offs   = cnt + N;        // N+1
  int* cursor = offs + (N + 1);
  int* csr    = cursor + N;     // E

  const int mblocks = (N + 63) / 64;

  // GRU layer 0
  gemm_k<true><<<dim3(mblocks, G3 / 64), 256, 0, stream>>>(x, w_ih0, b_ih0, gi, N, G3, IND);
  gru_scan<<<1, 256, 0, stream>>>(gi, w_hh0, b_hh0, h0, N);
  // GRU layer 1
  gemm_k<true><<<dim3(mblocks, G3 / 64), 256, 0, stream>>>(h0, w_ih1, b_ih1, gi, N, G3, HID);
  gru_scan<<<1, 256, 0, stream>>>(gi, w_hh1, b_hh1, h1, N);

  // CSR by dst (shared by both GAT layers)
  hipMemsetAsync(cnt, 0, (size_t)N * sizeof(int), stream);
  edge_count<<<(E + 255) / 256, 256, 0, stream>>>(ei, cnt, E);
  prefix_scan<<<1, 1024, 0, stream>>>(cnt, offs, cursor, N);
  edge_fill<<<(E + 255) / 256, 256, 0, stream>>>(ei, cursor, csr, E);

  // GAT layer 1
  gemm_k<false><<<dim3(mblocks, HC1 / 64), 256, 0, stream>>>(h1, W1, nullptr, hmm1, N, HC1, HID);
  att_dots<<<N, 4 * 64, 0, stream>>>(hmm1, att_src1, att_dst1, as1, ad1, 4, HID);
  gat_agg<<<N, HC1, 0, stream>>>(hmm1, as1, ad1, offs, csr, bias1, g1o, 4, 7, 1);

  // GAT layer 2
  gemm_k<false><<<dim3(mblocks, OUTD / 64), 256, 0, stream>>>(g1o, W2, nullptr, hmm2, N, OUTD, HC1);
  att_dots<<<N, 1 * 64, 0, stream>>>(hmm2, att_src2, att_dst2, as2, ad2, 1, OUTD);
  gat_agg<<<N, OUTD, 0, stream>>>(hmm2, as2, ad2, offs, csr, bias2, out, 1, 6, 0);
}

// Round 7
// 10972.833 us; speedup vs baseline: 1.2816x; 1.0340x over previous
//
#include <hip/hip_runtime.h>
#include <math.h>

#define NN_  10000
#define NE_  320000
#define IND  64
#define HID  128
#define G3   384   // 3*HID
#define HC1  512   // 4 heads * 128
#define OUTD 64

typedef _Float16 h2f __attribute__((ext_vector_type(2)));
union UH4 { uint4 u; h2f h[4]; };

__device__ __forceinline__ float leakyf_(float x){ return x>0.f ? x : 0.2f*x; }
__device__ __forceinline__ float fsig_(float x){ return 1.f/(1.f+__expf(-x)); }
__device__ __forceinline__ float ftanh_(float x){ float e=__expf(2.f*x); return 1.f-2.f/(e+1.f); }

// LDS-only barrier: waits LDS ops, does NOT drain vmcnt -> global prefetch
// loads / h1 stores stay in flight across the per-step barrier.
#define BARRIER_LDS() asm volatile("s_waitcnt lgkmcnt(0)\n\ts_barrier" ::: "memory")

// ---------------------------------------------------------------------------
// Generic tiled fp32 GEMM.  C[m,n] = sum_k A[m,k] * (TB ? B[n,k] : B[k,n]) + bias[n]
// ---------------------------------------------------------------------------
template<bool TB>
__global__ __launch_bounds__(256) void gemm_k(const float* __restrict__ A,
                                              const float* __restrict__ B,
                                              const float* __restrict__ bias,
                                              float* __restrict__ C,
                                              int M, int N, int K) {
  __shared__ float As[16][65];
  __shared__ float Bs[16][65];
  const int bm = blockIdx.x * 64, bn = blockIdx.y * 64;
  const int tid = threadIdx.x;
  const int tm = (tid >> 4) << 2, tn = (tid & 15) << 2;
  float acc[4][4] = {};
  const int row = tid & 63, kq = (tid >> 6) << 2;
  for (int k0 = 0; k0 < K; k0 += 16) {
    float4 av = make_float4(0.f, 0.f, 0.f, 0.f);
    const int m = bm + row;
    if (m < M) av = *(const float4*)(A + (size_t)m * K + k0 + kq);
    As[kq + 0][row] = av.x; As[kq + 1][row] = av.y;
    As[kq + 2][row] = av.z; As[kq + 3][row] = av.w;
    if (TB) {
      float4 bv = *(const float4*)(B + (size_t)(bn + row) * K + k0 + kq);
      Bs[kq + 0][row] = bv.x; Bs[kq + 1][row] = bv.y;
      Bs[kq + 2][row] = bv.z; Bs[kq + 3][row] = bv.w;
    } else {
      const int kr = tid >> 4, nq = (tid & 15) << 2;
      float4 bv = *(const float4*)(B + (size_t)(k0 + kr) * N + bn + nq);
      Bs[kr][nq + 0] = bv.x; Bs[kr][nq + 1] = bv.y;
      Bs[kr][nq + 2] = bv.z; Bs[kr][nq + 3] = bv.w;
    }
    __syncthreads();
#pragma unroll
    for (int kk = 0; kk < 16; kk++) {
      float a[4], b[4];
#pragma unroll
      for (int i = 0; i < 4; i++) a[i] = As[kk][tm + i];
#pragma unroll
      for (int j = 0; j < 4; j++) b[j] = Bs[kk][tn + j];
#pragma unroll
      for (int i = 0; i < 4; i++)
#pragma unroll
        for (int j = 0; j < 4; j++) acc[i][j] = fmaf(a[i], b[j], acc[i][j]);
    }
    __syncthreads();
  }
#pragma unroll
  for (int i = 0; i < 4; i++) {
    const int m = bm + tm + i;
    if (m < M) {
#pragma unroll
      for (int j = 0; j < 4; j++) {
        const int n = bn + tn + j;
        float v = acc[i][j];
        if (bias) v += bias[n];
        C[(size_t)m * N + n] = v;
      }
    }
  }
}

// ---------------------------------------------------------------------------
// FUSED two-layer GRU scan.  One block, 768 threads = 12 waves (3/SIMD).
//   grp = tid>>8:  0 = layer-0 (W_hh0 dots + gates)
//                  1 = layer-1 hh-path (W_hh1 . h1[s-2] partial dots)
//                  2 = layer-1 ih-path (W_ih1 . h0[s-1] partial dots + gates)
// Within a group: khalf=(local>>6)&1 K-split, j=(local&63)|((local>>7)<<6).
// Fused step s runs layer-0 step s and layer-1 step s-1 concurrently,
// sharing two LDS-only barriers.  h0 lives only in LDS; gi1 never exists.
// gi0 prefetch: nx/ny/nz temporaries, rotated ONLY in the combine phase
// (round-6 bug: loading directly into gx1 clobbered gi0[s+1] -> shifted
// input sequence -> absmax 4.6e-3).
// ---------------------------------------------------------------------------
__global__ __launch_bounds__(768, 1) void gru_fused(const float* __restrict__ gi0,
                                                    const float* __restrict__ w_hh0,
                                                    const float* __restrict__ b_hh0,
                                                    const float* __restrict__ w_ih1,
                                                    const float* __restrict__ b_ih1,
                                                    const float* __restrict__ w_hh1,
                                                    const float* __restrict__ b_hh1,
                                                    float* __restrict__ h1_out,
                                                    int T) {
  __shared__ _Float16 hbuf0[2][HID];   // fp16 h0, double-buffered
  __shared__ _Float16 hbuf1[2][HID];   // fp16 h1, double-buffered
  __shared__ float psum0[3][HID];      // L0 khalf-1 partials (r,z,n)
  __shared__ float psum1[9][HID];      // L1: [0-2]=ihB, [3-5]=hhA(+b_hh1), [6-8]=hhB

  const int tid   = threadIdx.x;
  const int grp   = tid >> 8;          // 0=L0, 1=L1h, 2=L1i
  const int local = tid & 255;
  const int khalf = (local >> 6) & 1;
  const int j     = (local & 63) | ((local >> 7) << 6);
  const int kbase = khalf * 64;

  const float* wsrc = (grp == 0) ? w_hh0 : (grp == 1 ? w_hh1 : w_ih1);
  const float* bsrc = (grp == 0) ? b_hh0 : (grp == 1 ? b_hh1 : b_ih1);
  const _Float16* hsrc = (grp == 1) ? &hbuf1[0][0] : &hbuf0[0][0];

  // load + convert this thread's half-rows of the 3 gates to packed fp16
  h2f wr[32], wz[32], wn[32];
#pragma unroll
  for (int i = 0; i < 16; i++) {
    float4 a = *(const float4*)(wsrc + (size_t)j * HID + kbase + i * 4);
    wr[2 * i]     = h2f{(_Float16)a.x, (_Float16)a.y};
    wr[2 * i + 1] = h2f{(_Float16)a.z, (_Float16)a.w};
  }
#pragma unroll
  for (int i = 0; i < 16; i++) {
    float4 a = *(const float4*)(wsrc + (size_t)(j + HID) * HID + kbase + i * 4);
    wz[2 * i]     = h2f{(_Float16)a.x, (_Float16)a.y};
    wz[2 * i + 1] = h2f{(_Float16)a.z, (_Float16)a.w};
  }
#pragma unroll
  for (int i = 0; i < 16; i++) {
    float4 a = *(const float4*)(wsrc + (size_t)(j + 2 * HID) * HID + kbase + i * 4);
    wn[2 * i]     = h2f{(_Float16)a.x, (_Float16)a.y};
    wn[2 * i + 1] = h2f{(_Float16)a.z, (_Float16)a.w};
  }
  // biases (khalf-0 threads only use them)
  const float b0 = bsrc[j];
  const float b1 = bsrc[j + HID];
  const float b2 = bsrc[j + 2 * HID];

  float hcur0 = 0.f, hcur1 = 0.f;
  if (tid < 64) {
    ((h2f*)&hbuf0[0][0])[tid] = h2f{(_Float16)0.f, (_Float16)0.f};
    ((h2f*)&hbuf1[1][0])[tid] = h2f{(_Float16)0.f, (_Float16)0.f};
  }
  BARRIER_LDS();

  // gi0 prefetch pipeline, 2 steps deep (L0 primaries only)
  float gx0, gy0, gz0, gx1, gy1, gz1;
  if (grp == 0 && khalf == 0) {
    const float* gp = gi0 + j;
    gx0 = gp[0]; gy0 = gp[HID]; gz0 = gp[2 * HID];
    gp = gi0 + G3 + j;
    gx1 = gp[0]; gy1 = gp[HID]; gz1 = gp[2 * HID];
  }

  for (int s = 0; s <= T; s++) {
    const int p = s & 1;
    const bool l0act = (s < T);
    const bool l1act = (s >= 1);
    const bool act = (grp == 0) ? l0act : l1act;

    float ar0 = 0.f, ar1 = 0.f, az0 = 0.f, az1 = 0.f, an0 = 0.f, an1 = 0.f;
    if (grp == 1 && khalf == 0) { ar0 = b0; az0 = b1; an0 = b2; }  // seed b_hh1

    // prefetch temporaries — must NOT clobber gx1 before rotation
    float nx = 0.f, ny = 0.f, nz = 0.f;

    if (act) {
      const uint4* hp = (const uint4*)(hsrc + (size_t)p * HID + kbase);
#pragma unroll
      for (int c = 0; c < 2; c++) {          // 2 chunks of 4 uint4 (64 B each)
        uint4 hv[4];
#pragma unroll
        for (int i = 0; i < 4; i++) hv[i] = hp[c * 4 + i];
        if (c == 0 && grp == 0 && khalf == 0) {   // issue gi0 prefetch early
          const int tp = (s + 2 < T) ? (s + 2) : (T - 1);
          const float* gp = gi0 + (size_t)tp * G3 + j;
          nx = gp[0]; ny = gp[HID]; nz = gp[2 * HID];  // consumed 2 steps later
        }
#pragma unroll
        for (int i = 0; i < 4; i++) {
          UH4 v; v.u = hv[i];
#pragma unroll
          for (int q = 0; q < 4; q++) {
            const int k = c * 16 + i * 4 + q;
            const h2f hh = v.h[q];
            if (k & 1) {
              ar1 = __builtin_amdgcn_fdot2(wr[k], hh, ar1, false);
              az1 = __builtin_amdgcn_fdot2(wz[k], hh, az1, false);
              an1 = __builtin_amdgcn_fdot2(wn[k], hh, an1, false);
            } else {
              ar0 = __builtin_amdgcn_fdot2(wr[k], hh, ar0, false);
              az0 = __builtin_amdgcn_fdot2(wz[k], hh, az0, false);
              an0 = __builtin_amdgcn_fdot2(wn[k], hh, an0, false);
            }
          }
        }
      }
      // export partials (everyone except the two primary roles)
      if (grp == 0) {
        if (khalf == 1) {
          psum0[0][j] = ar0 + ar1; psum0[1][j] = az0 + az1; psum0[2][j] = an0 + an1;
        }
      } else if (grp == 2) {
        if (khalf == 1) {
          psum1[0][j] = ar0 + ar1; psum1[1][j] = az0 + az1; psum1[2][j] = an0 + an1;
        }
      } else {  // grp 1 (hh-path): both halves export
        const int base = (khalf == 0) ? 3 : 6;
        psum1[base + 0][j] = ar0 + ar1;
        psum1[base + 1][j] = az0 + az1;
        psum1[base + 2][j] = an0 + an1;
      }
    }
    BARRIER_LDS();

    if (grp == 0 && khalf == 0 && l0act) {      // layer-0 gates -> h0[s]
      const float r = fsig_(gx0 + b0 + ar0 + ar1 + psum0[0][j]);
      const float z = fsig_(gy0 + b1 + az0 + az1 + psum0[1][j]);
      const float n = ftanh_(gz0 + r * (b2 + an0 + an1 + psum0[2][j]));
      hcur0 = (1.f - z) * n + z * hcur0;
      hbuf0[p ^ 1][j] = (_Float16)hcur0;
      gx0 = gx1; gy0 = gy1; gz0 = gz1;          // rotate prefetch pipeline
      gx1 = nx;  gy1 = ny;  gz1 = nz;
    }
    if (grp == 2 && khalf == 0 && l1act) {      // layer-1 gates -> h1[s-1]
      const float i_r = ar0 + ar1 + psum1[0][j] + b0;
      const float i_z = az0 + az1 + psum1[1][j] + b1;
      const float i_n = an0 + an1 + psum1[2][j] + b2;
      const float h_r = psum1[3][j] + psum1[6][j];
      const float h_z = psum1[4][j] + psum1[7][j];
      const float h_n = psum1[5][j] + psum1[8][j];
      const float r = fsig_(i_r + h_r);
      const float z = fsig_(i_z + h_z);
      const float n = ftanh_(i_n + r * h_n);
      hcur1 = (1.f - z) * n + z * hcur1;
      hbuf1[p ^ 1][j] = (_Float16)hcur1;
      h1_out[(size_t)(s - 1) * HID + j] = hcur1;
    }
    BARRIER_LDS();
  }
}

// ---------------------------------------------------------------------------
// Attention per-node dots: a_s[n,h] = feat[n,h,:].att_src[h,:]  (same for dst)
// ---------------------------------------------------------------------------
__global__ void att_dots(const float* __restrict__ feat,
                         const float* __restrict__ att_src,
                         const float* __restrict__ att_dst,
                         float* __restrict__ a_s, float* __restrict__ a_d,
                         int heads, int C) {
  const int n = blockIdx.x;
  const int h = threadIdx.x >> 6;
  const int lane = threadIdx.x & 63;
  float ss = 0.f, dd = 0.f;
  const float* f = feat + (size_t)n * heads * C + h * C;
  for (int c = lane; c < C; c += 64) {
    const float v = f[c];
    ss = fmaf(v, att_src[h * C + c], ss);
    dd = fmaf(v, att_dst[h * C + c], dd);
  }
#pragma unroll
  for (int o = 32; o > 0; o >>= 1) {
    ss += __shfl_down(ss, o);
    dd += __shfl_down(dd, o);
  }
  if (lane == 0) { a_s[n * heads + h] = ss; a_d[n * heads + h] = dd; }
}

// ---------------------------------------------------------------------------
// CSR build (edge_index arrives as int32: ei[0..E) = src, ei[E..2E) = dst)
// ---------------------------------------------------------------------------
__global__ void edge_count(const int* __restrict__ ei, int* __restrict__ cnt, int E) {
  const int e = blockIdx.x * 256 + threadIdx.x;
  if (e < E) atomicAdd(&cnt[ei[E + e]], 1);
}

__global__ __launch_bounds__(1024) void prefix_scan(const int* __restrict__ cnt,
                                                    int* __restrict__ offs,
                                                    int* __restrict__ cursor, int N) {
  __shared__ int buf[1024];
  __shared__ int carry;
  const int tid = threadIdx.x;
  if (tid == 0) carry = 0;
  __syncthreads();
  for (int base = 0; base < N; base += 1024) {
    const int i = base + tid;
    const int v = (i < N) ? cnt[i] : 0;
    buf[tid] = v;
    __syncthreads();
    for (int d = 1; d < 1024; d <<= 1) {
      int t = 0;
      if (tid >= d) t = buf[tid - d];
      __syncthreads();
      buf[tid] += t;
      __syncthreads();
    }
    const int incl = buf[tid] + carry;
    if (i < N) { offs[i] = incl - v; cursor[i] = incl - v; }
    __syncthreads();
    if (tid == 1023) carry = incl;
    __syncthreads();
  }
  if (tid == 0) offs[N] = carry;
}

__global__ void edge_fill(const int* __restrict__ ei, int* __restrict__ cursor,
                          int* __restrict__ csr, int E) {
  const int e = blockIdx.x * 256 + threadIdx.x;
  if (e < E) {
    const int d = ei[E + e];
    const int s = ei[e];
    const int pos = atomicAdd(&cursor[d], 1);
    csr[pos] = s;
  }
}

// ---------------------------------------------------------------------------
// GAT softmax-aggregation.  One block per dst node; blockDim = heads<<cshift.
// ---------------------------------------------------------------------------
__global__ void gat_agg(const float* __restrict__ feat,
                        const float* __restrict__ a_s, const float* __restrict__ a_d,
                        const int* __restrict__ offs, const int* __restrict__ csr,
                        const float* __restrict__ bias, float* __restrict__ out,
                        int heads, int cshift, int do_relu) {
  const int n = blockIdx.x;
  const int t = threadIdx.x;
  const int HC = blockDim.x;
  const int h = t >> cshift;
  const int beg = offs[n], end = offs[n + 1];
  const float ad = a_d[n * heads + h];
  const float self_e = leakyf_(a_s[n * heads + h] + ad);
  float m = self_e;
  for (int i = beg; i < end; i++) {
    const int s = csr[i];
    m = fmaxf(m, leakyf_(a_s[s * heads + h] + ad));
  }
  float den = expf(self_e - m);
  float acc = den * feat[(size_t)n * HC + t];
  for (int i = beg; i < end; i++) {
    const int s = csr[i];
    const float wgt = expf(leakyf_(a_s[s * heads + h] + ad) - m);
    den += wgt;
    acc = fmaf(wgt, feat[(size_t)s * HC + t], acc);
  }
  float o = acc / den + bias[t];
  if (do_relu) o = fmaxf(o, 0.f);
  out[(size_t)n * HC + t] = o;
}

// ---------------------------------------------------------------------------
extern "C" void kernel_launch(void* const* d_in, const int* in_sizes, int n_in,
                              void* d_out, int out_size, void* d_ws, size_t ws_size,
                              hipStream_t stream) {
  const float* x        = (const float*)d_in[0];
  const int*   ei       = (const int*)d_in[1];   // int64 inputs arrive as int32
  const float* w_ih0    = (const float*)d_in[2];
  const float* w_hh0    = (const float*)d_in[3];
  const float* b_ih0    = (const float*)d_in[4];
  const float* b_hh0    = (const float*)d_in[5];
  const float* w_ih1    = (const float*)d_in[6];
  const float* w_hh1    = (const float*)d_in[7];
  const float* b_ih1    = (const float*)d_in[8];
  const float* b_hh1    = (const float*)d_in[9];
  const float* W1       = (const float*)d_in[10];
  const float* att_src1 = (const float*)d_in[11];
  const float* att_dst1 = (const float*)d_in[12];
  const float* bias1    = (const float*)d_in[13];
  const float* W2       = (const float*)d_in[14];
  const float* att_src2 = (const float*)d_in[15];
  const float* att_dst2 = (const float*)d_in[16];
  const float* bias2    = (const float*)d_in[17];
  float* out = (float*)d_out;

  const int N = NN_;
  const int E = in_sizes[1] / 2;

  // ---- workspace layout with overlays ----
  float* f    = (float*)d_ws;
  float* gi   = f;                         // region A (gi0; dead after scan)
  float* hmm1 = f;                         // = A, reused for GAT1 features
  float* h1   = f + (size_t)N * HC1;                    // B
  float* g1o  = h1 + (size_t)N * HID;                   // C
  float* hmm2 = g1o + (size_t)N * HC1;                  // D
  float* as1  = hmm2 + (size_t)N * OUTD;
  float* ad1  = as1 + (size_t)N * 4;
  float* as2  = ad1 + (size_t)N * 4;
  float* ad2  = as2 + (size_t)N;
  int* cnt    = (int*)(ad2 + (size_t)N);
  int* offs   = cnt + N;        // N+1
  int* cursor = offs + (N + 1);
  int* csr    = cursor + N;     // E

  const int mblocks = (N + 63) / 64;

  // GRU: gi0 GEMM, then fused two-layer scan (h0 never leaves LDS)
  gemm_k<true><<<dim3(mblocks, G3 / 64), 256, 0, stream>>>(x, w_ih0, b_ih0, gi, N, G3, IND);
  gru_fused<<<1, 768, 0, stream>>>(gi, w_hh0, b_hh0, w_ih1, b_ih1, w_hh1, b_hh1, h1, N);

  // CSR by dst (shared by both GAT layers)
  hipMemsetAsync(cnt, 0, (size_t)N * sizeof(int), stream);
  edge_count<<<(E + 255) / 256, 256, 0, stream>>>(ei, cnt, E);
  prefix_scan<<<1, 1024, 0, stream>>>(cnt, offs, cursor, N);
  edge_fill<<<(E + 255) / 256, 256, 0, stream>>>(ei, cursor, csr, E);

  // GAT layer 1
  gemm_k<false><<<dim3(mblocks, HC1 / 64), 256, 0, stream>>>(h1, W1, nullptr, hmm1, N, HC1, HID);
  att_dots<<<N, 4 * 64, 0, stream>>>(hmm1, att_src1, att_dst1, as1, ad1, 4, HID);
  gat_agg<<<N, HC1, 0, stream>>>(hmm1, as1, ad1, offs, csr, bias1, g1o, 4, 7, 1);

  // GAT layer 2
  gemm_k<false><<<dim3(mblocks, OUTD / 64), 256, 0, stream>>>(g1o, W2, nullptr, hmm2, N, OUTD, HC1);
  att_dots<<<N, 1 * 64, 0, stream>>>(hmm2, att_src2, att_dst2, as2, ad2, 1, OUTD);
  gat_agg<<<N, OUTD, 0, stream>>>(hmm2, as2, ad2, offs, csr, bias2, out, 1, 6, 0);
}

// Round 8
// 7674.744 us; speedup vs baseline: 1.8324x; 1.4297x over previous
//
#include <hip/hip_runtime.h>
#include <math.h>

#define NN_  10000
#define NE_  320000
#define IND  64
#define HID  128
#define G3   384   // 3*HID
#define HC1  512   // 4 heads * 128
#define OUTD 64

typedef _Float16 h2f __attribute__((ext_vector_type(2)));
union UH4 { uint4 u; h2f h[4]; };

__device__ __forceinline__ float leakyf_(float x){ return x>0.f ? x : 0.2f*x; }
__device__ __forceinline__ float fsig_(float x){ return 1.f/(1.f+__expf(-x)); }
__device__ __forceinline__ float ftanh_(float x){ float e=__expf(2.f*x); return 1.f-2.f/(e+1.f); }

// LDS-only barrier: waits LDS ops, does NOT drain vmcnt.
#define BARRIER_LDS() asm volatile("s_waitcnt lgkmcnt(0)\n\ts_barrier" ::: "memory")

// agent-scope (device) atomic helpers for cross-block streams
__device__ __forceinline__ float ld_agent(const float* p) {
  return __hip_atomic_load(p, __ATOMIC_RELAXED, __HIP_MEMORY_SCOPE_AGENT);
}
__device__ __forceinline__ void st_agent(float* p, float v) {
  __hip_atomic_store(p, v, __ATOMIC_RELAXED, __HIP_MEMORY_SCOPE_AGENT);
}
__device__ __forceinline__ int ld_ctr(const int* p) {
  return __hip_atomic_load(p, __ATOMIC_ACQUIRE, __HIP_MEMORY_SCOPE_AGENT);
}
__device__ __forceinline__ void st_ctr(int* p, int v) {
  __hip_atomic_store(p, v, __ATOMIC_RELEASE, __HIP_MEMORY_SCOPE_AGENT);
}

// ---------------------------------------------------------------------------
// Generic tiled fp32 GEMM.  C[m,n] = sum_k A[m,k] * (TB ? B[n,k] : B[k,n]) + bias[n]
// ---------------------------------------------------------------------------
template<bool TB>
__global__ __launch_bounds__(256) void gemm_k(const float* __restrict__ A,
                                              const float* __restrict__ B,
                                              const float* __restrict__ bias,
                                              float* __restrict__ C,
                                              int M, int N, int K) {
  __shared__ float As[16][65];
  __shared__ float Bs[16][65];
  const int bm = blockIdx.x * 64, bn = blockIdx.y * 64;
  const int tid = threadIdx.x;
  const int tm = (tid >> 4) << 2, tn = (tid & 15) << 2;
  float acc[4][4] = {};
  const int row = tid & 63, kq = (tid >> 6) << 2;
  for (int k0 = 0; k0 < K; k0 += 16) {
    float4 av = make_float4(0.f, 0.f, 0.f, 0.f);
    const int m = bm + row;
    if (m < M) av = *(const float4*)(A + (size_t)m * K + k0 + kq);
    As[kq + 0][row] = av.x; As[kq + 1][row] = av.y;
    As[kq + 2][row] = av.z; As[kq + 3][row] = av.w;
    if (TB) {
      float4 bv = *(const float4*)(B + (size_t)(bn + row) * K + k0 + kq);
      Bs[kq + 0][row] = bv.x; Bs[kq + 1][row] = bv.y;
      Bs[kq + 2][row] = bv.z; Bs[kq + 3][row] = bv.w;
    } else {
      const int kr = tid >> 4, nq = (tid & 15) << 2;
      float4 bv = *(const float4*)(B + (size_t)(k0 + kr) * N + bn + nq);
      Bs[kr][nq + 0] = bv.x; Bs[kr][nq + 1] = bv.y;
      Bs[kr][nq + 2] = bv.z; Bs[kr][nq + 3] = bv.w;
    }
    __syncthreads();
#pragma unroll
    for (int kk = 0; kk < 16; kk++) {
      float a[4], b[4];
#pragma unroll
      for (int i = 0; i < 4; i++) a[i] = As[kk][tm + i];
#pragma unroll
      for (int j = 0; j < 4; j++) b[j] = Bs[kk][tn + j];
#pragma unroll
      for (int i = 0; i < 4; i++)
#pragma unroll
        for (int j = 0; j < 4; j++) acc[i][j] = fmaf(a[i], b[j], acc[i][j]);
    }
    __syncthreads();
  }
#pragma unroll
  for (int i = 0; i < 4; i++) {
    const int m = bm + tm + i;
    if (m < M) {
#pragma unroll
      for (int j = 0; j < 4; j++) {
        const int n = bn + tn + j;
        float v = acc[i][j];
        if (bias) v += bias[n];
        C[(size_t)m * N + n] = v;
      }
    }
  }
}

// ---------------------------------------------------------------------------
// Pipelined two-layer GRU across 4 CUs.  4 blocks x 256 threads:
//  block 0: layer-0 scan (round-5 structure) -> h0 stream + progress ctr
//  blocks 1,2: gi1 factories, parity-split over t (no recurrence, 2x slack):
//              gi1[t] = W_ih1 . h0[t] + b_ih1 -> gi1 stream + ctrs
//  block 3: layer-1 scan consuming gi1 stream -> h1_out
// Cross-block traffic via agent-scope atomics (XCD-safe).  Each block keeps
// the round-5 K-split structure: thread owns 3 gate rows x half-K as 96
// packed-fp16 VGPRs; broadcast h from its OWN CU's LDS (own LDS pipe).
// ---------------------------------------------------------------------------
__global__ __launch_bounds__(256, 1) void gru_pipe(const float* __restrict__ gi0,
                                                   const float* __restrict__ w_hh0,
                                                   const float* __restrict__ b_hh0,
                                                   const float* __restrict__ w_ih1,
                                                   const float* __restrict__ b_ih1,
                                                   const float* __restrict__ w_hh1,
                                                   const float* __restrict__ b_hh1,
                                                   float* h0_st, float* gi1_st,
                                                   int* ctr,           // [0]=prog0 [1]=pf0 [2]=pf1
                                                   float* __restrict__ h1_out,
                                                   int T) {
  __shared__ _Float16 hbuf[2][HID];
  __shared__ float psum[3][HID];

  const int bid   = blockIdx.x;
  const int tid   = threadIdx.x;
  const int khalf = (tid >> 6) & 1;
  const int j     = (tid & 63) | ((tid >> 7) << 6);
  const int kbase = khalf * 64;

  const float* wsrc = (bid == 0) ? w_hh0 : (bid == 3 ? w_hh1 : w_ih1);
  const float* bsrc = (bid == 0) ? b_hh0 : (bid == 3 ? b_hh1 : b_ih1);

  // load + convert this thread's half-rows of the 3 gates to packed fp16
  h2f wr[32], wz[32], wn[32];
#pragma unroll
  for (int i = 0; i < 16; i++) {
    float4 a = *(const float4*)(wsrc + (size_t)j * HID + kbase + i * 4);
    wr[2 * i]     = h2f{(_Float16)a.x, (_Float16)a.y};
    wr[2 * i + 1] = h2f{(_Float16)a.z, (_Float16)a.w};
  }
#pragma unroll
  for (int i = 0; i < 16; i++) {
    float4 a = *(const float4*)(wsrc + (size_t)(j + HID) * HID + kbase + i * 4);
    wz[2 * i]     = h2f{(_Float16)a.x, (_Float16)a.y};
    wz[2 * i + 1] = h2f{(_Float16)a.z, (_Float16)a.w};
  }
#pragma unroll
  for (int i = 0; i < 16; i++) {
    float4 a = *(const float4*)(wsrc + (size_t)(j + 2 * HID) * HID + kbase + i * 4);
    wn[2 * i]     = h2f{(_Float16)a.x, (_Float16)a.y};
    wn[2 * i + 1] = h2f{(_Float16)a.z, (_Float16)a.w};
  }
  const float b0 = bsrc[j];
  const float b1 = bsrc[j + HID];
  const float b2 = bsrc[j + 2 * HID];

  // dot over this thread's K-half from an LDS fp16 vector at 'hp16'
  auto dot_half = [&](const _Float16* hp16, float& r, float& z, float& n) {
    const uint4* hp = (const uint4*)(hp16 + kbase);
    float ar0 = 0.f, ar1 = 0.f, az0 = 0.f, az1 = 0.f, an0 = 0.f, an1 = 0.f;
#pragma unroll
    for (int c = 0; c < 2; c++) {
      uint4 hv[4];
#pragma unroll
      for (int i = 0; i < 4; i++) hv[i] = hp[c * 4 + i];
#pragma unroll
      for (int i = 0; i < 4; i++) {
        UH4 v; v.u = hv[i];
#pragma unroll
        for (int q = 0; q < 4; q++) {
          const int k = c * 16 + i * 4 + q;
          const h2f hh = v.h[q];
          if (k & 1) {
            ar1 = __builtin_amdgcn_fdot2(wr[k], hh, ar1, false);
            az1 = __builtin_amdgcn_fdot2(wz[k], hh, az1, false);
            an1 = __builtin_amdgcn_fdot2(wn[k], hh, an1, false);
          } else {
            ar0 = __builtin_amdgcn_fdot2(wr[k], hh, ar0, false);
            az0 = __builtin_amdgcn_fdot2(wz[k], hh, az0, false);
            an0 = __builtin_amdgcn_fdot2(wn[k], hh, an0, false);
          }
        }
      }
    }
    r = ar0 + ar1; z = az0 + az1; n = an0 + an1;
  };

  if (bid == 0 || bid == 3) {
    // ---------------- scan roles (layer 0 / layer 1) ----------------
    float hcur = 0.f;
    if (khalf == 0) hbuf[0][j] = (_Float16)0.f;
    BARRIER_LDS();

    // gi prefetch pipeline, 2 deep (primaries only)
    float gx0, gy0, gz0, gx1, gy1, gz1;
    if (bid == 3 && tid == 0) {            // ensure gi1[0..2] published
      while (ld_ctr(&ctr[1]) < 3) {}
      while (ld_ctr(&ctr[2]) < 2) {}
    }
    if (bid == 3) __syncthreads();
    if (khalf == 0) {
      if (bid == 0) {
        const float* gp = gi0 + j;
        gx0 = gp[0]; gy0 = gp[HID]; gz0 = gp[2 * HID];
        gp = gi0 + G3 + j;
        gx1 = gp[0]; gy1 = gp[HID]; gz1 = gp[2 * HID];
      } else {
        const float* gp = gi1_st + j;
        gx0 = ld_agent(gp); gy0 = ld_agent(gp + HID); gz0 = ld_agent(gp + 2 * HID);
        gp = gi1_st + G3 + j;
        gx1 = ld_agent(gp); gy1 = ld_agent(gp + HID); gz1 = ld_agent(gp + 2 * HID);
      }
    }

    for (int t = 0; t < T; t++) {
      const int p = t & 1;
      float nx = 0.f, ny = 0.f, nz = 0.f;
      // issue prefetch for t+2 (primaries), then dots
      if (khalf == 0) {
        const int tp = (t + 2 < T) ? (t + 2) : (T - 1);
        if (bid == 0) {
          const float* gp = gi0 + (size_t)tp * G3 + j;
          nx = gp[0]; ny = gp[HID]; nz = gp[2 * HID];
        } else {
          const float* gp = gi1_st + (size_t)tp * G3 + j;
          nx = ld_agent(gp); ny = ld_agent(gp + HID); nz = ld_agent(gp + 2 * HID);
        }
      }
      float dr, dz, dn;
      dot_half(&hbuf[p][0], dr, dz, dn);
      if (khalf == 1) { psum[0][j] = dr; psum[1][j] = dz; psum[2][j] = dn; }
      BARRIER_LDS();
      if (khalf == 0) {
        const float r = fsig_(gx0 + b0 + dr + psum[0][j]);
        const float z = fsig_(gy0 + b1 + dz + psum[1][j]);
        const float n = ftanh_(gz0 + r * (b2 + dn + psum[2][j]));
        hcur = (1.f - z) * n + z * hcur;
        hbuf[p ^ 1][j] = (_Float16)hcur;
        if (bid == 0) st_agent(&h0_st[(size_t)t * HID + j], hcur);
        else          h1_out[(size_t)t * HID + j] = hcur;
        gx0 = gx1; gy0 = gy1; gz0 = gz1;
        gx1 = nx;  gy1 = ny;  gz1 = nz;
      }
      // consumer: poll (combine phase, off the load path) for next prefetch
      if (bid == 3 && tid == 0) {
        int s = t + 3; if (s > T - 1) s = T - 1;
        while (ld_ctr(&ctr[1 + (s & 1)]) < s + 1) {}
      }
      BARRIER_LDS();
      if (bid == 0 && (t & 7) == 7) {        // publish h0 progress
        __syncthreads();                      // drains vmcnt in all waves
        if (tid == 0) st_ctr(&ctr[0], t + 1);
      }
    }
    if (bid == 0) {
      __syncthreads();
      if (tid == 0) st_ctr(&ctr[0], T);
    }
  } else {
    // ---------------- factory roles (gi1 for parity f) ----------------
    const int f = bid - 1;                    // 0 or 1
    _Float16* hstage = &hbuf[0][0];           // single staging buffer
    int done = 0;
    for (int t = f; t < T; t += 2) {
      if (tid == 0) { while (ld_ctr(&ctr[0]) < t + 1) {} }
      __syncthreads();
      if (tid < HID) hstage[tid] = (_Float16)ld_agent(&h0_st[(size_t)t * HID + tid]);
      BARRIER_LDS();
      float dr, dz, dn;
      dot_half(hstage, dr, dz, dn);
      if (khalf == 1) { psum[0][j] = dr; psum[1][j] = dz; psum[2][j] = dn; }
      BARRIER_LDS();
      if (khalf == 0) {
        float* gp = gi1_st + (size_t)t * G3 + j;
        st_agent(gp,           dr + psum[0][j] + b0);
        st_agent(gp + HID,     dz + psum[1][j] + b1);
        st_agent(gp + 2 * HID, dn + psum[2][j] + b2);
      }
      done++;
      if ((done & 3) == 0) {                  // publish every 4 processed
        __syncthreads();
        if (tid == 0) st_ctr(&ctr[1 + f], t + 1);
      }
    }
    __syncthreads();
    if (tid == 0) st_ctr(&ctr[1 + f], T);
  }
}

// ---------------------------------------------------------------------------
// Attention per-node dots: a_s[n,h] = feat[n,h,:].att_src[h,:]  (same for dst)
// ---------------------------------------------------------------------------
__global__ void att_dots(const float* __restrict__ feat,
                         const float* __restrict__ att_src,
                         const float* __restrict__ att_dst,
                         float* __restrict__ a_s, float* __restrict__ a_d,
                         int heads, int C) {
  const int n = blockIdx.x;
  const int h = threadIdx.x >> 6;
  const int lane = threadIdx.x & 63;
  float ss = 0.f, dd = 0.f;
  const float* f = feat + (size_t)n * heads * C + h * C;
  for (int c = lane; c < C; c += 64) {
    const float v = f[c];
    ss = fmaf(v, att_src[h * C + c], ss);
    dd = fmaf(v, att_dst[h * C + c], dd);
  }
#pragma unroll
  for (int o = 32; o > 0; o >>= 1) {
    ss += __shfl_down(ss, o);
    dd += __shfl_down(dd, o);
  }
  if (lane == 0) { a_s[n * heads + h] = ss; a_d[n * heads + h] = dd; }
}

// ---------------------------------------------------------------------------
// CSR build (edge_index arrives as int32: ei[0..E) = src, ei[E..2E) = dst)
// ---------------------------------------------------------------------------
__global__ void edge_count(const int* __restrict__ ei, int* __restrict__ cnt, int E) {
  const int e = blockIdx.x * 256 + threadIdx.x;
  if (e < E) atomicAdd(&cnt[ei[E + e]], 1);
}

__global__ __launch_bounds__(1024) void prefix_scan(const int* __restrict__ cnt,
                                                    int* __restrict__ offs,
                                                    int* __restrict__ cursor, int N) {
  __shared__ int buf[1024];
  __shared__ int carry;
  const int tid = threadIdx.x;
  if (tid == 0) carry = 0;
  __syncthreads();
  for (int base = 0; base < N; base += 1024) {
    const int i = base + tid;
    const int v = (i < N) ? cnt[i] : 0;
    buf[tid] = v;
    __syncthreads();
    for (int d = 1; d < 1024; d <<= 1) {
      int t = 0;
      if (tid >= d) t = buf[tid - d];
      __syncthreads();
      buf[tid] += t;
      __syncthreads();
    }
    const int incl = buf[tid] + carry;
    if (i < N) { offs[i] = incl - v; cursor[i] = incl - v; }
    __syncthreads();
    if (tid == 1023) carry = incl;
    __syncthreads();
  }
  if (tid == 0) offs[N] = carry;
}

__global__ void edge_fill(const int* __restrict__ ei, int* __restrict__ cursor,
                          int* __restrict__ csr, int E) {
  const int e = blockIdx.x * 256 + threadIdx.x;
  if (e < E) {
    const int d = ei[E + e];
    const int s = ei[e];
    const int pos = atomicAdd(&cursor[d], 1);
    csr[pos] = s;
  }
}

// ---------------------------------------------------------------------------
// GAT softmax-aggregation.  One block per dst node; blockDim = heads<<cshift.
// ---------------------------------------------------------------------------
__global__ void gat_agg(const float* __restrict__ feat,
                        const float* __restrict__ a_s, const float* __restrict__ a_d,
                        const int* __restrict__ offs, const int* __restrict__ csr,
                        const float* __restrict__ bias, float* __restrict__ out,
                        int heads, int cshift, int do_relu) {
  const int n = blockIdx.x;
  const int t = threadIdx.x;
  const int HC = blockDim.x;
  const int h = t >> cshift;
  const int beg = offs[n], end = offs[n + 1];
  const float ad = a_d[n * heads + h];
  const float self_e = leakyf_(a_s[n * heads + h] + ad);
  float m = self_e;
  for (int i = beg; i < end; i++) {
    const int s = csr[i];
    m = fmaxf(m, leakyf_(a_s[s * heads + h] + ad));
  }
  float den = expf(self_e - m);
  float acc = den * feat[(size_t)n * HC + t];
  for (int i = beg; i < end; i++) {
    const int s = csr[i];
    const float wgt = expf(leakyf_(a_s[s * heads + h] + ad) - m);
    den += wgt;
    acc = fmaf(wgt, feat[(size_t)s * HC + t], acc);
  }
  float o = acc / den + bias[t];
  if (do_relu) o = fmaxf(o, 0.f);
  out[(size_t)n * HC + t] = o;
}

// ---------------------------------------------------------------------------
extern "C" void kernel_launch(void* const* d_in, const int* in_sizes, int n_in,
                              void* d_out, int out_size, void* d_ws, size_t ws_size,
                              hipStream_t stream) {
  const float* x        = (const float*)d_in[0];
  const int*   ei       = (const int*)d_in[1];   // int64 inputs arrive as int32
  const float* w_ih0    = (const float*)d_in[2];
  const float* w_hh0    = (const float*)d_in[3];
  const float* b_ih0    = (const float*)d_in[4];
  const float* b_hh0    = (const float*)d_in[5];
  const float* w_ih1    = (const float*)d_in[6];
  const float* w_hh1    = (const float*)d_in[7];
  const float* b_ih1    = (const float*)d_in[8];
  const float* b_hh1    = (const float*)d_in[9];
  const float* W1       = (const float*)d_in[10];
  const float* att_src1 = (const float*)d_in[11];
  const float* att_dst1 = (const float*)d_in[12];
  const float* bias1    = (const float*)d_in[13];
  const float* W2       = (const float*)d_in[14];
  const float* att_src2 = (const float*)d_in[15];
  const float* att_dst2 = (const float*)d_in[16];
  const float* bias2    = (const float*)d_in[17];
  float* out = (float*)d_out;

  const int N = NN_;
  const int E = in_sizes[1] / 2;

  // ---- workspace layout with overlays (peak ~54 MB) ----
  float* f    = (float*)d_ws;
  float* gi   = f;                         // region A (gi0; dead after scan)
  float* hmm1 = f;                         // = A, reused for GAT1 features
  float* h1   = f + (size_t)N * HC1;                    // B
  float* g1o  = h1 + (size_t)N * HID;                   // C (post-scan)
  float* hmm2 = g1o + (size_t)N * HC1;                  // D
  float* as1  = hmm2 + (size_t)N * OUTD;
  float* ad1  = as1 + (size_t)N * 4;
  float* as2  = ad1 + (size_t)N * 4;
  float* ad2  = as2 + (size_t)N;
  int* cnt    = (int*)(ad2 + (size_t)N);
  int* offs   = cnt + N;        // N+1
  int* cursor = offs + (N + 1);
  int* csr    = cursor + N;     // E
  int* ctr    = csr + E;        // 3 ints: prog0, pf0, pf1
  // scan-time streams overlay region C (g1o): N*HID + N*G3 = N*HC1 floats ✓
  float* h0_st  = g1o;
  float* gi1_st = g1o + (size_t)N * HID;

  const int mblocks = (N + 63) / 64;

  // GRU: gi0 GEMM, zero counters, then 4-CU pipelined two-layer scan
  gemm_k<true><<<dim3(mblocks, G3 / 64), 256, 0, stream>>>(x, w_ih0, b_ih0, gi, N, G3, IND);
  hipMemsetAsync(ctr, 0, 3 * sizeof(int), stream);
  gru_pipe<<<4, 256, 0, stream>>>(gi, w_hh0, b_hh0, w_ih1, b_ih1, w_hh1, b_hh1,
                                  h0_st, gi1_st, ctr, h1, N);

  // CSR by dst (shared by both GAT layers)
  hipMemsetAsync(cnt, 0, (size_t)N * sizeof(int), stream);
  edge_count<<<(E + 255) / 256, 256, 0, stream>>>(ei, cnt, E);
  prefix_scan<<<1, 1024, 0, stream>>>(cnt, offs, cursor, N);
  edge_fill<<<(E + 255) / 256, 256, 0, stream>>>(ei, cursor, csr, E);

  // GAT layer 1
  gemm_k<false><<<dim3(mblocks, HC1 / 64), 256, 0, stream>>>(h1, W1, nullptr, hmm1, N, HC1, HID);
  att_dots<<<N, 4 * 64, 0, stream>>>(hmm1, att_src1, att_dst1, as1, ad1, 4, HID);
  gat_agg<<<N, HC1, 0, stream>>>(hmm1, as1, ad1, offs, csr, bias1, g1o, 4, 7, 1);

  // GAT layer 2
  gemm_k<false><<<dim3(mblocks, OUTD / 64), 256, 0, stream>>>(g1o, W2, nullptr, hmm2, N, OUTD, HC1);
  att_dots<<<N, 1 * 64, 0, stream>>>(hmm2, att_src2, att_dst2, as2, ad2, 1, OUTD);
  gat_agg<<<N, OUTD, 0, stream>>>(hmm2, as2, ad2, offs, csr, bias2, out, 1, 6, 0);
}

// Round 9
// 7245.629 us; speedup vs baseline: 1.9409x; 1.0592x over previous
//
#include <hip/hip_runtime.h>
#include <math.h>

#define NN_  10000
#define NE_  320000
#define IND  64
#define HID  128
#define G3   384   // 3*HID
#define HC1  512   // 4 heads * 128
#define OUTD 64

typedef _Float16 h2f __attribute__((ext_vector_type(2)));
union UH4 { uint4 u; h2f h[4]; };

__device__ __forceinline__ float leakyf_(float x){ return x>0.f ? x : 0.2f*x; }
__device__ __forceinline__ float fsig_(float x){ return 1.f/(1.f+__expf(-x)); }
__device__ __forceinline__ float ftanh_(float x){ float e=__expf(2.f*x); return 1.f-2.f/(e+1.f); }

// LDS-only barrier: waits LDS ops, does NOT drain vmcnt.
#define BARRIER_LDS() asm volatile("s_waitcnt lgkmcnt(0)\n\ts_barrier" ::: "memory")
#define WAIT_VM0()    asm volatile("s_waitcnt vmcnt(0)" ::: "memory")

// agent-scope (device) atomic helpers for cross-block streams
__device__ __forceinline__ float ld_agent(const float* p) {
  return __hip_atomic_load(p, __ATOMIC_RELAXED, __HIP_MEMORY_SCOPE_AGENT);
}
__device__ __forceinline__ void st_agent(float* p, float v) {
  __hip_atomic_store(p, v, __ATOMIC_RELAXED, __HIP_MEMORY_SCOPE_AGENT);
}
__device__ __forceinline__ unsigned ld_agent_u32(const unsigned* p) {
  return __hip_atomic_load(p, __ATOMIC_RELAXED, __HIP_MEMORY_SCOPE_AGENT);
}
__device__ __forceinline__ void st_agent_u32(unsigned* p, unsigned v) {
  __hip_atomic_store(p, v, __ATOMIC_RELAXED, __HIP_MEMORY_SCOPE_AGENT);
}
__device__ __forceinline__ int ld_ctr(const int* p) {
  return __hip_atomic_load(p, __ATOMIC_ACQUIRE, __HIP_MEMORY_SCOPE_AGENT);
}
__device__ __forceinline__ void st_ctr(int* p, int v) {
  __hip_atomic_store(p, v, __ATOMIC_RELEASE, __HIP_MEMORY_SCOPE_AGENT);
}

// ---------------------------------------------------------------------------
// Generic tiled fp32 GEMM.  C[m,n] = sum_k A[m,k] * (TB ? B[n,k] : B[k,n]) + bias[n]
// ---------------------------------------------------------------------------
template<bool TB>
__global__ __launch_bounds__(256) void gemm_k(const float* __restrict__ A,
                                              const float* __restrict__ B,
                                              const float* __restrict__ bias,
                                              float* __restrict__ C,
                                              int M, int N, int K) {
  __shared__ float As[16][65];
  __shared__ float Bs[16][65];
  const int bm = blockIdx.x * 64, bn = blockIdx.y * 64;
  const int tid = threadIdx.x;
  const int tm = (tid >> 4) << 2, tn = (tid & 15) << 2;
  float acc[4][4] = {};
  const int row = tid & 63, kq = (tid >> 6) << 2;
  for (int k0 = 0; k0 < K; k0 += 16) {
    float4 av = make_float4(0.f, 0.f, 0.f, 0.f);
    const int m = bm + row;
    if (m < M) av = *(const float4*)(A + (size_t)m * K + k0 + kq);
    As[kq + 0][row] = av.x; As[kq + 1][row] = av.y;
    As[kq + 2][row] = av.z; As[kq + 3][row] = av.w;
    if (TB) {
      float4 bv = *(const float4*)(B + (size_t)(bn + row) * K + k0 + kq);
      Bs[kq + 0][row] = bv.x; Bs[kq + 1][row] = bv.y;
      Bs[kq + 2][row] = bv.z; Bs[kq + 3][row] = bv.w;
    } else {
      const int kr = tid >> 4, nq = (tid & 15) << 2;
      float4 bv = *(const float4*)(B + (size_t)(k0 + kr) * N + bn + nq);
      Bs[kr][nq + 0] = bv.x; Bs[kr][nq + 1] = bv.y;
      Bs[kr][nq + 2] = bv.z; Bs[kr][nq + 3] = bv.w;
    }
    __syncthreads();
#pragma unroll
    for (int kk = 0; kk < 16; kk++) {
      float a[4], b[4];
#pragma unroll
      for (int i = 0; i < 4; i++) a[i] = As[kk][tm + i];
#pragma unroll
      for (int j = 0; j < 4; j++) b[j] = Bs[kk][tn + j];
#pragma unroll
      for (int i = 0; i < 4; i++)
#pragma unroll
        for (int j = 0; j < 4; j++) acc[i][j] = fmaf(a[i], b[j], acc[i][j]);
    }
    __syncthreads();
  }
#pragma unroll
  for (int i = 0; i < 4; i++) {
    const int m = bm + tm + i;
    if (m < M) {
#pragma unroll
      for (int j = 0; j < 4; j++) {
        const int n = bn + tn + j;
        float v = acc[i][j];
        if (bias) v += bias[n];
        C[(size_t)m * N + n] = v;
      }
    }
  }
}

// ---------------------------------------------------------------------------
// Pipelined two-layer GRU across 4 CUs.  4 blocks x 256 threads:
//  block 0: layer-0 scan -> fp16 h0 stream (stored by wave 1, whose vmcnt
//           holds ONLY stores -> cheap drain) + progress ctr every 4 steps
//  blocks 1,2: gi1 factories (parity-split), publish every 2 items
//  block 3: layer-1 scan consuming gi1; polls ctrs once per 8 steps
// Cross-block traffic via agent-scope atomics (XCD-safe).
// ---------------------------------------------------------------------------
__global__ __launch_bounds__(256, 1) void gru_pipe(const float* __restrict__ gi0,
                                                   const float* __restrict__ w_hh0,
                                                   const float* __restrict__ b_hh0,
                                                   const float* __restrict__ w_ih1,
                                                   const float* __restrict__ b_ih1,
                                                   const float* __restrict__ w_hh1,
                                                   const float* __restrict__ b_hh1,
                                                   unsigned* h0_st16, float* gi1_st,
                                                   int* ctr,           // [0]=prog0 [1]=pf0 [2]=pf1
                                                   float* __restrict__ h1_out,
                                                   int T) {
  __shared__ _Float16 hbuf[2][HID];
  __shared__ float psum[3][HID];

  const int bid   = blockIdx.x;
  const int tid   = threadIdx.x;
  const int khalf = (tid >> 6) & 1;
  const int j     = (tid & 63) | ((tid >> 7) << 6);
  const int kbase = khalf * 64;

  const float* wsrc = (bid == 0) ? w_hh0 : (bid == 3 ? w_hh1 : w_ih1);
  const float* bsrc = (bid == 0) ? b_hh0 : (bid == 3 ? b_hh1 : b_ih1);

  // load + convert this thread's half-rows of the 3 gates to packed fp16
  h2f wr[32], wz[32], wn[32];
#pragma unroll
  for (int i = 0; i < 16; i++) {
    float4 a = *(const float4*)(wsrc + (size_t)j * HID + kbase + i * 4);
    wr[2 * i]     = h2f{(_Float16)a.x, (_Float16)a.y};
    wr[2 * i + 1] = h2f{(_Float16)a.z, (_Float16)a.w};
  }
#pragma unroll
  for (int i = 0; i < 16; i++) {
    float4 a = *(const float4*)(wsrc + (size_t)(j + HID) * HID + kbase + i * 4);
    wz[2 * i]     = h2f{(_Float16)a.x, (_Float16)a.y};
    wz[2 * i + 1] = h2f{(_Float16)a.z, (_Float16)a.w};
  }
#pragma unroll
  for (int i = 0; i < 16; i++) {
    float4 a = *(const float4*)(wsrc + (size_t)(j + 2 * HID) * HID + kbase + i * 4);
    wn[2 * i]     = h2f{(_Float16)a.x, (_Float16)a.y};
    wn[2 * i + 1] = h2f{(_Float16)a.z, (_Float16)a.w};
  }
  const float b0 = bsrc[j];
  const float b1 = bsrc[j + HID];
  const float b2 = bsrc[j + 2 * HID];

  // dot over this thread's K-half from an LDS fp16 vector at 'hp16'
  auto dot_half = [&](const _Float16* hp16, float& r, float& z, float& n) {
    const uint4* hp = (const uint4*)(hp16 + kbase);
    float ar0 = 0.f, ar1 = 0.f, az0 = 0.f, az1 = 0.f, an0 = 0.f, an1 = 0.f;
#pragma unroll
    for (int c = 0; c < 2; c++) {
      uint4 hv[4];
#pragma unroll
      for (int i = 0; i < 4; i++) hv[i] = hp[c * 4 + i];
#pragma unroll
      for (int i = 0; i < 4; i++) {
        UH4 v; v.u = hv[i];
#pragma unroll
        for (int q = 0; q < 4; q++) {
          const int k = c * 16 + i * 4 + q;
          const h2f hh = v.h[q];
          if (k & 1) {
            ar1 = __builtin_amdgcn_fdot2(wr[k], hh, ar1, false);
            az1 = __builtin_amdgcn_fdot2(wz[k], hh, az1, false);
            an1 = __builtin_amdgcn_fdot2(wn[k], hh, an1, false);
          } else {
            ar0 = __builtin_amdgcn_fdot2(wr[k], hh, ar0, false);
            az0 = __builtin_amdgcn_fdot2(wz[k], hh, az0, false);
            an0 = __builtin_amdgcn_fdot2(wn[k], hh, an0, false);
          }
        }
      }
    }
    r = ar0 + ar1; z = az0 + az1; n = an0 + an1;
  };

  if (bid == 0 || bid == 3) {
    // ---------------- scan roles (layer 0 / layer 1) ----------------
    float hcur = 0.f;
    if (khalf == 0) hbuf[0][j] = (_Float16)0.f;
    BARRIER_LDS();

    if (bid == 3 && tid == 0) {            // ensure gi1[0..10] published
      const int need0 = (T < 11) ? T : 11;
      while (ld_ctr(&ctr[1]) < need0) {}
      while (ld_ctr(&ctr[2]) < need0) {}
    }
    if (bid == 3) __syncthreads();

    // gi prefetch pipeline, 2 deep (primaries only)
    float gx0, gy0, gz0, gx1, gy1, gz1;
    if (khalf == 0) {
      if (bid == 0) {
        const float* gp = gi0 + j;
        gx0 = gp[0]; gy0 = gp[HID]; gz0 = gp[2 * HID];
        gp = gi0 + G3 + j;
        gx1 = gp[0]; gy1 = gp[HID]; gz1 = gp[2 * HID];
      } else {
        const float* gp = gi1_st + j;
        gx0 = ld_agent(gp); gy0 = ld_agent(gp + HID); gz0 = ld_agent(gp + 2 * HID);
        gp = gi1_st + G3 + j;
        gx1 = ld_agent(gp); gy1 = ld_agent(gp + HID); gz1 = ld_agent(gp + 2 * HID);
      }
    }

    for (int t = 0; t < T; t++) {
      const int p = t & 1;
      float nx = 0.f, ny = 0.f, nz = 0.f;
      // issue prefetch for t+2 (primaries), then dots
      if (khalf == 0) {
        const int tp = (t + 2 < T) ? (t + 2) : (T - 1);
        if (bid == 0) {
          const float* gp = gi0 + (size_t)tp * G3 + j;
          nx = gp[0]; ny = gp[HID]; nz = gp[2 * HID];
        } else {
          const float* gp = gi1_st + (size_t)tp * G3 + j;
          nx = ld_agent(gp); ny = ld_agent(gp + HID); nz = ld_agent(gp + 2 * HID);
        }
      }
      float dr, dz, dn;
      dot_half(&hbuf[p][0], dr, dz, dn);
      if (khalf == 1) { psum[0][j] = dr; psum[1][j] = dz; psum[2][j] = dn; }
      BARRIER_LDS();
      if (khalf == 0) {
        const float r = fsig_(gx0 + b0 + dr + psum[0][j]);
        const float z = fsig_(gy0 + b1 + dz + psum[1][j]);
        const float n = ftanh_(gz0 + r * (b2 + dn + psum[2][j]));
        hcur = (1.f - z) * n + z * hcur;
        hbuf[p ^ 1][j] = (_Float16)hcur;
        if (bid == 3) h1_out[(size_t)t * HID + j] = hcur;
        gx0 = gx1; gy0 = gy1; gz0 = gz1;
        gx1 = nx;  gy1 = ny;  gz1 = nz;
      }
      // consumer: poll once per 8 steps (combine phase, amortized)
      if (bid == 3 && tid == 0 && (t & 7) == 0) {
        int need = t + 11; if (need > T) need = T;
        while (ld_ctr(&ctr[1]) < need) {}
        while (ld_ctr(&ctr[2]) < need) {}
      }
      BARRIER_LDS();
      // producer: wave 1 (no global loads in its vmcnt) exports fp16 h0
      if (bid == 0 && tid >= 64 && tid < 128) {
        const int idx = tid - 64;
        unsigned v = *(const unsigned*)&hbuf[p ^ 1][2 * idx];
        st_agent_u32(&h0_st16[(size_t)t * 64 + idx], v);
        if ((t & 3) == 3 || t == T - 1) {
          WAIT_VM0();                          // drains only wave-1 stores
          if (tid == 64) st_ctr(&ctr[0], t + 1);
        }
      }
    }
  } else {
    // ---------------- factory roles (gi1 for parity f) ----------------
    const int f = bid - 1;                    // 0 or 1
    _Float16* hstage = &hbuf[0][0];           // single staging buffer
    int done = 0;
    for (int t = f; t < T; t += 2) {
      if (tid == 0) { while (ld_ctr(&ctr[0]) < t + 1) {} }
      __syncthreads();
      if (tid < 64)
        ((unsigned*)hstage)[tid] = ld_agent_u32(&h0_st16[(size_t)t * 64 + tid]);
      BARRIER_LDS();
      float dr, dz, dn;
      dot_half(hstage, dr, dz, dn);
      if (khalf == 1) { psum[0][j] = dr; psum[1][j] = dz; psum[2][j] = dn; }
      BARRIER_LDS();
      if (khalf == 0) {
        float* gp = gi1_st + (size_t)t * G3 + j;
        st_agent(gp,           dr + psum[0][j] + b0);
        st_agent(gp + HID,     dz + psum[1][j] + b1);
        st_agent(gp + 2 * HID, dn + psum[2][j] + b2);
      }
      done++;
      if ((done & 1) == 0) {                  // publish every 2 processed
        __syncthreads();
        if (tid == 0) st_ctr(&ctr[1 + f], t + 1);
      }
    }
    __syncthreads();
    if (tid == 0) st_ctr(&ctr[1 + f], T);
  }
}

// ---------------------------------------------------------------------------
// Attention per-node dots: a_s[n,h] = feat[n,h,:].att_src[h,:]  (same for dst)
// ---------------------------------------------------------------------------
__global__ void att_dots(const float* __restrict__ feat,
                         const float* __restrict__ att_src,
                         const float* __restrict__ att_dst,
                         float* __restrict__ a_s, float* __restrict__ a_d,
                         int heads, int C) {
  const int n = blockIdx.x;
  const int h = threadIdx.x >> 6;
  const int lane = threadIdx.x & 63;
  float ss = 0.f, dd = 0.f;
  const float* f = feat + (size_t)n * heads * C + h * C;
  for (int c = lane; c < C; c += 64) {
    const float v = f[c];
    ss = fmaf(v, att_src[h * C + c], ss);
    dd = fmaf(v, att_dst[h * C + c], dd);
  }
#pragma unroll
  for (int o = 32; o > 0; o >>= 1) {
    ss += __shfl_down(ss, o);
    dd += __shfl_down(dd, o);
  }
  if (lane == 0) { a_s[n * heads + h] = ss; a_d[n * heads + h] = dd; }
}

// ---------------------------------------------------------------------------
// CSR build (edge_index arrives as int32: ei[0..E) = src, ei[E..2E) = dst)
// ---------------------------------------------------------------------------
__global__ void edge_count(const int* __restrict__ ei, int* __restrict__ cnt, int E) {
  const int e = blockIdx.x * 256 + threadIdx.x;
  if (e < E) atomicAdd(&cnt[ei[E + e]], 1);
}

__global__ __launch_bounds__(1024) void prefix_scan(const int* __restrict__ cnt,
                                                    int* __restrict__ offs,
                                                    int* __restrict__ cursor, int N) {
  __shared__ int buf[1024];
  __shared__ int carry;
  const int tid = threadIdx.x;
  if (tid == 0) carry = 0;
  __syncthreads();
  for (int base = 0; base < N; base += 1024) {
    const int i = base + tid;
    const int v = (i < N) ? cnt[i] : 0;
    buf[tid] = v;
    __syncthreads();
    for (int d = 1; d < 1024; d <<= 1) {
      int t = 0;
      if (tid >= d) t = buf[tid - d];
      __syncthreads();
      buf[tid] += t;
      __syncthreads();
    }
    const int incl = buf[tid] + carry;
    if (i < N) { offs[i] = incl - v; cursor[i] = incl - v; }
    __syncthreads();
    if (tid == 1023) carry = incl;
    __syncthreads();
  }
  if (tid == 0) offs[N] = carry;
}

__global__ void edge_fill(const int* __restrict__ ei, int* __restrict__ cursor,
                          int* __restrict__ csr, int E) {
  const int e = blockIdx.x * 256 + threadIdx.x;
  if (e < E) {
    const int d = ei[E + e];
    const int s = ei[e];
    const int pos = atomicAdd(&cursor[d], 1);
    csr[pos] = s;
  }
}

// ---------------------------------------------------------------------------
// GAT softmax-aggregation.  One block per dst node; blockDim = heads<<cshift.
// ---------------------------------------------------------------------------
__global__ void gat_agg(const float* __restrict__ feat,
                        const float* __restrict__ a_s, const float* __restrict__ a_d,
                        const int* __restrict__ offs, const int* __restrict__ csr,
                        const float* __restrict__ bias, float* __restrict__ out,
                        int heads, int cshift, int do_relu) {
  const int n = blockIdx.x;
  const int t = threadIdx.x;
  const int HC = blockDim.x;
  const int h = t >> cshift;
  const int beg = offs[n], end = offs[n + 1];
  const float ad = a_d[n * heads + h];
  const float self_e = leakyf_(a_s[n * heads + h] + ad);
  float m = self_e;
  for (int i = beg; i < end; i++) {
    const int s = csr[i];
    m = fmaxf(m, leakyf_(a_s[s * heads + h] + ad));
  }
  float den = expf(self_e - m);
  float acc = den * feat[(size_t)n * HC + t];
  for (int i = beg; i < end; i++) {
    const int s = csr[i];
    const float wgt = expf(leakyf_(a_s[s * heads + h] + ad) - m);
    den += wgt;
    acc = fmaf(wgt, feat[(size_t)s * HC + t], acc);
  }
  float o = acc / den + bias[t];
  if (do_relu) o = fmaxf(o, 0.f);
  out[(size_t)n * HC + t] = o;
}

// ---------------------------------------------------------------------------
extern "C" void kernel_launch(void* const* d_in, const int* in_sizes, int n_in,
                              void* d_out, int out_size, void* d_ws, size_t ws_size,
                              hipStream_t stream) {
  const float* x        = (const float*)d_in[0];
  const int*   ei       = (const int*)d_in[1];   // int64 inputs arrive as int32
  const float* w_ih0    = (const float*)d_in[2];
  const float* w_hh0    = (const float*)d_in[3];
  const float* b_ih0    = (const float*)d_in[4];
  const float* b_hh0    = (const float*)d_in[5];
  const float* w_ih1    = (const float*)d_in[6];
  const float* w_hh1    = (const float*)d_in[7];
  const float* b_ih1    = (const float*)d_in[8];
  const float* b_hh1    = (const float*)d_in[9];
  const float* W1       = (const float*)d_in[10];
  const float* att_src1 = (const float*)d_in[11];
  const float* att_dst1 = (const float*)d_in[12];
  const float* bias1    = (const float*)d_in[13];
  const float* W2       = (const float*)d_in[14];
  const float* att_src2 = (const float*)d_in[15];
  const float* att_dst2 = (const float*)d_in[16];
  const float* bias2    = (const float*)d_in[17];
  float* out = (float*)d_out;

  const int N = NN_;
  const int E = in_sizes[1] / 2;

  // ---- workspace layout with overlays (peak ~54 MB) ----
  float* f    = (float*)d_ws;
  float* gi   = f;                         // region A (gi0; dead after scan)
  float* hmm1 = f;                         // = A, reused for GAT1 features
  float* h1   = f + (size_t)N * HC1;                    // B
  float* g1o  = h1 + (size_t)N * HID;                   // C (post-scan)
  float* hmm2 = g1o + (size_t)N * HC1;                  // D
  float* as1  = hmm2 + (size_t)N * OUTD;
  float* ad1  = as1 + (size_t)N * 4;
  float* as2  = ad1 + (size_t)N * 4;
  float* ad2  = as2 + (size_t)N;
  int* cnt    = (int*)(ad2 + (size_t)N);
  int* offs   = cnt + N;        // N+1
  int* cursor = offs + (N + 1);
  int* csr    = cursor + N;     // E
  int* ctr    = csr + E;        // 3 ints: prog0, pf0, pf1
  // scan-time streams overlay region C (g1o): N*64 uints (fp16 h0) + N*G3
  // floats (gi1) = N*448 float-slots <= N*HC1 ✓
  unsigned* h0_st16 = (unsigned*)g1o;
  float*    gi1_st  = g1o + (size_t)N * 64;

  const int mblocks = (N + 63) / 64;

  // GRU: gi0 GEMM, zero counters, then 4-CU pipelined two-layer scan
  gemm_k<true><<<dim3(mblocks, G3 / 64), 256, 0, stream>>>(x, w_ih0, b_ih0, gi, N, G3, IND);
  hipMemsetAsync(ctr, 0, 3 * sizeof(int), stream);
  gru_pipe<<<4, 256, 0, stream>>>(gi, w_hh0, b_hh0, w_ih1, b_ih1, w_hh1, b_hh1,
                                  h0_st16, gi1_st, ctr, h1, N);

  // CSR by dst (shared by both GAT layers)
  hipMemsetAsync(cnt, 0, (size_t)N * sizeof(int), stream);
  edge_count<<<(E + 255) / 256, 256, 0, stream>>>(ei, cnt, E);
  prefix_scan<<<1, 1024, 0, stream>>>(cnt, offs, cursor, N);
  edge_fill<<<(E + 255) / 256, 256, 0, stream>>>(ei, cursor, csr, E);

  // GAT layer 1
  gemm_k<false><<<dim3(mblocks, HC1 / 64), 256, 0, stream>>>(h1, W1, nullptr, hmm1, N, HC1, HID);
  att_dots<<<N, 4 * 64, 0, stream>>>(hmm1, att_src1, att_dst1, as1, ad1, 4, HID);
  gat_agg<<<N, HC1, 0, stream>>>(hmm1, as1, ad1, offs, csr, bias1, g1o, 4, 7, 1);

  // GAT layer 2
  gemm_k<false><<<dim3(mblocks, OUTD / 64), 256, 0, stream>>>(g1o, W2, nullptr, hmm2, N, OUTD, HC1);
  att_dots<<<N, 1 * 64, 0, stream>>>(hmm2, att_src2, att_dst2, as2, ad2, 1, OUTD);
  gat_agg<<<N, OUTD, 0, stream>>>(hmm2, as2, ad2, offs, csr, bias2, out, 1, 6, 0);
}

// Round 10
// 6913.977 us; speedup vs baseline: 2.0340x; 1.0480x over previous
//
#include <hip/hip_runtime.h>
#include <math.h>

#define NN_  10000
#define NE_  320000
#define IND  64
#define HID  128
#define G3   384   // 3*HID
#define HC1  512   // 4 heads * 128
#define OUTD 64

typedef _Float16 h2f __attribute__((ext_vector_type(2)));
union UH4 { uint4 u; h2f h[4]; };

__device__ __forceinline__ float leakyf_(float x){ return x>0.f ? x : 0.2f*x; }
__device__ __forceinline__ float fsig_(float x){ return 1.f/(1.f+__expf(-x)); }
__device__ __forceinline__ float ftanh_(float x){ float e=__expf(2.f*x); return 1.f-2.f/(e+1.f); }

// LDS-only barrier: waits LDS ops, does NOT drain vmcnt.
#define BARRIER_LDS() asm volatile("s_waitcnt lgkmcnt(0)\n\ts_barrier" ::: "memory")
#define WAIT_VM0()    asm volatile("s_waitcnt vmcnt(0)" ::: "memory")

// agent-scope (device) atomic helpers for cross-block streams
__device__ __forceinline__ float ld_agent(const float* p) {
  return __hip_atomic_load(p, __ATOMIC_RELAXED, __HIP_MEMORY_SCOPE_AGENT);
}
__device__ __forceinline__ void st_agent(float* p, float v) {
  __hip_atomic_store(p, v, __ATOMIC_RELAXED, __HIP_MEMORY_SCOPE_AGENT);
}
__device__ __forceinline__ unsigned ld_agent_u32(const unsigned* p) {
  return __hip_atomic_load(p, __ATOMIC_RELAXED, __HIP_MEMORY_SCOPE_AGENT);
}
__device__ __forceinline__ void st_agent_u32(unsigned* p, unsigned v) {
  __hip_atomic_store(p, v, __ATOMIC_RELAXED, __HIP_MEMORY_SCOPE_AGENT);
}
__device__ __forceinline__ int ld_ctr(const int* p) {
  return __hip_atomic_load(p, __ATOMIC_ACQUIRE, __HIP_MEMORY_SCOPE_AGENT);
}
__device__ __forceinline__ void st_ctr(int* p, int v) {
  __hip_atomic_store(p, v, __ATOMIC_RELEASE, __HIP_MEMORY_SCOPE_AGENT);
}

// ---------------------------------------------------------------------------
// Generic tiled fp32 GEMM.  C[m,n] = sum_k A[m,k] * (TB ? B[n,k] : B[k,n]) + bias[n]
// ---------------------------------------------------------------------------
template<bool TB>
__global__ __launch_bounds__(256) void gemm_k(const float* __restrict__ A,
                                              const float* __restrict__ B,
                                              const float* __restrict__ bias,
                                              float* __restrict__ C,
                                              int M, int N, int K) {
  __shared__ float As[16][65];
  __shared__ float Bs[16][65];
  const int bm = blockIdx.x * 64, bn = blockIdx.y * 64;
  const int tid = threadIdx.x;
  const int tm = (tid >> 4) << 2, tn = (tid & 15) << 2;
  float acc[4][4] = {};
  const int row = tid & 63, kq = (tid >> 6) << 2;
  for (int k0 = 0; k0 < K; k0 += 16) {
    float4 av = make_float4(0.f, 0.f, 0.f, 0.f);
    const int m = bm + row;
    if (m < M) av = *(const float4*)(A + (size_t)m * K + k0 + kq);
    As[kq + 0][row] = av.x; As[kq + 1][row] = av.y;
    As[kq + 2][row] = av.z; As[kq + 3][row] = av.w;
    if (TB) {
      float4 bv = *(const float4*)(B + (size_t)(bn + row) * K + k0 + kq);
      Bs[kq + 0][row] = bv.x; Bs[kq + 1][row] = bv.y;
      Bs[kq + 2][row] = bv.z; Bs[kq + 3][row] = bv.w;
    } else {
      const int kr = tid >> 4, nq = (tid & 15) << 2;
      float4 bv = *(const float4*)(B + (size_t)(k0 + kr) * N + bn + nq);
      Bs[kr][nq + 0] = bv.x; Bs[kr][nq + 1] = bv.y;
      Bs[kr][nq + 2] = bv.z; Bs[kr][nq + 3] = bv.w;
    }
    __syncthreads();
#pragma unroll
    for (int kk = 0; kk < 16; kk++) {
      float a[4], b[4];
#pragma unroll
      for (int i = 0; i < 4; i++) a[i] = As[kk][tm + i];
#pragma unroll
      for (int j = 0; j < 4; j++) b[j] = Bs[kk][tn + j];
#pragma unroll
      for (int i = 0; i < 4; i++)
#pragma unroll
        for (int j = 0; j < 4; j++) acc[i][j] = fmaf(a[i], b[j], acc[i][j]);
    }
    __syncthreads();
  }
#pragma unroll
  for (int i = 0; i < 4; i++) {
    const int m = bm + tm + i;
    if (m < M) {
#pragma unroll
      for (int j = 0; j < 4; j++) {
        const int n = bn + tn + j;
        float v = acc[i][j];
        if (bias) v += bias[n];
        C[(size_t)m * N + n] = v;
      }
    }
  }
}

// ---------------------------------------------------------------------------
// Pipelined two-layer GRU across 4 CUs.  4 blocks x 256 threads:
//  block 0: layer-0 scan -> fp16 h0 stream + progress ctr every 4 steps
//  blocks 1,2: gi1 factories (parity-split), publish every 2 items
//  block 3: layer-1 scan consuming gi1; polls ctrs once per 16 steps
// gi prefetch: unroll-by-2 with TWO independent register sets (gA even
// steps, gB odd), reloaded after consumption -> the s_waitcnt for a
// prefetch lands ~2 full steps after issue (round-9 rotation forced the
// wait within the issuing step -> cross-XCD latency exposed on block 3).
// ---------------------------------------------------------------------------
__global__ __launch_bounds__(256, 1) void gru_pipe(const float* __restrict__ gi0,
                                                   const float* __restrict__ w_hh0,
                                                   const float* __restrict__ b_hh0,
                                                   const float* __restrict__ w_ih1,
                                                   const float* __restrict__ b_ih1,
                                                   const float* __restrict__ w_hh1,
                                                   const float* __restrict__ b_hh1,
                                                   unsigned* h0_st16, float* gi1_st,
                                                   int* ctr,           // [0]=prog0 [1]=pf0 [2]=pf1
                                                   float* __restrict__ h1_out,
                                                   int T) {
  __shared__ _Float16 hbuf[2][HID];
  __shared__ float psum[3][HID];

  const int bid   = blockIdx.x;
  const int tid   = threadIdx.x;
  const int khalf = (tid >> 6) & 1;
  const int j     = (tid & 63) | ((tid >> 7) << 6);
  const int kbase = khalf * 64;

  const float* wsrc = (bid == 0) ? w_hh0 : (bid == 3 ? w_hh1 : w_ih1);
  const float* bsrc = (bid == 0) ? b_hh0 : (bid == 3 ? b_hh1 : b_ih1);

  // load + convert this thread's half-rows of the 3 gates to packed fp16
  h2f wr[32], wz[32], wn[32];
#pragma unroll
  for (int i = 0; i < 16; i++) {
    float4 a = *(const float4*)(wsrc + (size_t)j * HID + kbase + i * 4);
    wr[2 * i]     = h2f{(_Float16)a.x, (_Float16)a.y};
    wr[2 * i + 1] = h2f{(_Float16)a.z, (_Float16)a.w};
  }
#pragma unroll
  for (int i = 0; i < 16; i++) {
    float4 a = *(const float4*)(wsrc + (size_t)(j + HID) * HID + kbase + i * 4);
    wz[2 * i]     = h2f{(_Float16)a.x, (_Float16)a.y};
    wz[2 * i + 1] = h2f{(_Float16)a.z, (_Float16)a.w};
  }
#pragma unroll
  for (int i = 0; i < 16; i++) {
    float4 a = *(const float4*)(wsrc + (size_t)(j + 2 * HID) * HID + kbase + i * 4);
    wn[2 * i]     = h2f{(_Float16)a.x, (_Float16)a.y};
    wn[2 * i + 1] = h2f{(_Float16)a.z, (_Float16)a.w};
  }
  const float b0 = bsrc[j];
  const float b1 = bsrc[j + HID];
  const float b2 = bsrc[j + 2 * HID];

  // dot over this thread's K-half from an LDS fp16 vector at 'hp16'
  auto dot_half = [&](const _Float16* hp16, float& r, float& z, float& n) {
    const uint4* hp = (const uint4*)(hp16 + kbase);
    float ar0 = 0.f, ar1 = 0.f, az0 = 0.f, az1 = 0.f, an0 = 0.f, an1 = 0.f;
#pragma unroll
    for (int c = 0; c < 2; c++) {
      uint4 hv[4];
#pragma unroll
      for (int i = 0; i < 4; i++) hv[i] = hp[c * 4 + i];
#pragma unroll
      for (int i = 0; i < 4; i++) {
        UH4 v; v.u = hv[i];
#pragma unroll
        for (int q = 0; q < 4; q++) {
          const int k = c * 16 + i * 4 + q;
          const h2f hh = v.h[q];
          if (k & 1) {
            ar1 = __builtin_amdgcn_fdot2(wr[k], hh, ar1, false);
            az1 = __builtin_amdgcn_fdot2(wz[k], hh, az1, false);
            an1 = __builtin_amdgcn_fdot2(wn[k], hh, an1, false);
          } else {
            ar0 = __builtin_amdgcn_fdot2(wr[k], hh, ar0, false);
            az0 = __builtin_amdgcn_fdot2(wz[k], hh, az0, false);
            an0 = __builtin_amdgcn_fdot2(wn[k], hh, an0, false);
          }
        }
      }
    }
    r = ar0 + ar1; z = az0 + az1; n = an0 + an1;
  };

  if (bid == 0 || bid == 3) {
    // ---------------- scan roles (layer 0 / layer 3 = layer-1) ----------------
    const float* gsrc = (bid == 0) ? gi0 : gi1_st;
    float hcur = 0.f;
    if (khalf == 0) hbuf[0][j] = (_Float16)0.f;
    BARRIER_LDS();

    if (bid == 3 && tid == 0) {            // ensure gi1[0..1] published
      while (ld_ctr(&ctr[1]) < 1) {}
      while (ld_ctr(&ctr[2]) < 2) {}
    }
    if (bid == 3) __syncthreads();

    // two independent prefetch register sets: gA (even t), gB (odd t)
    float gxA, gyA, gzA, gxB, gyB, gzB;
    if (khalf == 0) {
      const float* gp = gsrc + j;
      gxA = gp[0]; gyA = gp[HID]; gzA = gp[2 * HID];
      gp = gsrc + G3 + j;
      gxB = gp[0]; gyB = gp[HID]; gzB = gp[2 * HID];
    }

    for (int t = 0; t < T; t += 2) {
      // ======== sub-step A: time t (even), reads hbuf[0], writes hbuf[1] ====
      {
        float dr, dz, dn;
        dot_half(&hbuf[0][0], dr, dz, dn);
        if (khalf == 1) { psum[0][j] = dr; psum[1][j] = dz; psum[2][j] = dn; }
        BARRIER_LDS();
        if (khalf == 0) {
          const float r = fsig_(gxA + b0 + dr + psum[0][j]);
          const float z = fsig_(gyA + b1 + dz + psum[1][j]);
          const float n = ftanh_(gzA + r * (b2 + dn + psum[2][j]));
          hcur = (1.f - z) * n + z * hcur;
          hbuf[1][j] = (_Float16)hcur;
          if (bid == 3) h1_out[(size_t)t * HID + j] = hcur;
          // reload gA for t+2 (consumed 2 full steps later -> latency hidden)
          const int tp = (t + 2 < T) ? (t + 2) : 0;
          const float* gp = gsrc + (size_t)tp * G3 + j;
          gxA = gp[0]; gyA = gp[HID]; gzA = gp[2 * HID];
        }
        // consumer: poll once per 16 steps (amortized)
        if (bid == 3 && tid == 0 && (t & 15) == 0) {
          int need = t + 19; if (need > T) need = T;
          while (ld_ctr(&ctr[1]) < need) {}
          while (ld_ctr(&ctr[2]) < need) {}
        }
        BARRIER_LDS();
        // producer: wave 1 (stores only in its vmcnt) exports fp16 h0[t]
        if (bid == 0 && tid >= 64 && tid < 128) {
          const int idx = tid - 64;
          unsigned v = *(const unsigned*)&hbuf[1][2 * idx];
          st_agent_u32(&h0_st16[(size_t)t * 64 + idx], v);
        }
      }
      // ======== sub-step B: time t+1 (odd), reads hbuf[1], writes hbuf[0] ===
      {
        const int tc = t + 1;
        float dr, dz, dn;
        dot_half(&hbuf[1][0], dr, dz, dn);
        if (khalf == 1) { psum[0][j] = dr; psum[1][j] = dz; psum[2][j] = dn; }
        BARRIER_LDS();
        if (khalf == 0) {
          const float r = fsig_(gxB + b0 + dr + psum[0][j]);
          const float z = fsig_(gyB + b1 + dz + psum[1][j]);
          const float n = ftanh_(gzB + r * (b2 + dn + psum[2][j]));
          hcur = (1.f - z) * n + z * hcur;
          hbuf[0][j] = (_Float16)hcur;
          if (bid == 3) h1_out[(size_t)tc * HID + j] = hcur;
          // reload gB for t+3
          const int tp = (tc + 2 < T) ? (tc + 2) : 0;
          const float* gp = gsrc + (size_t)tp * G3 + j;
          gxB = gp[0]; gyB = gp[HID]; gzB = gp[2 * HID];
        }
        BARRIER_LDS();
        if (bid == 0 && tid >= 64 && tid < 128) {
          const int idx = tid - 64;
          unsigned v = *(const unsigned*)&hbuf[0][2 * idx];
          st_agent_u32(&h0_st16[(size_t)tc * 64 + idx], v);
          if ((tc & 3) == 3) {
            WAIT_VM0();                        // drains only wave-1 stores
            if (tid == 64) st_ctr(&ctr[0], tc + 1);
          }
        }
      }
    }
    if (bid == 0 && tid >= 64 && tid < 128) {  // final publish
      WAIT_VM0();
      if (tid == 64) st_ctr(&ctr[0], T);
    }
  } else {
    // ---------------- factory roles (gi1 for parity f) ----------------
    const int f = bid - 1;                    // 0 or 1
    _Float16* hstage = &hbuf[0][0];           // single staging buffer
    int done = 0;
    for (int t = f; t < T; t += 2) {
      if (tid == 0) { while (ld_ctr(&ctr[0]) < t + 1) {} }
      __syncthreads();
      if (tid < 64)
        ((unsigned*)hstage)[tid] = ld_agent_u32(&h0_st16[(size_t)t * 64 + tid]);
      BARRIER_LDS();
      float dr, dz, dn;
      dot_half(hstage, dr, dz, dn);
      if (khalf == 1) { psum[0][j] = dr; psum[1][j] = dz; psum[2][j] = dn; }
      BARRIER_LDS();
      if (khalf == 0) {
        float* gp = gi1_st + (size_t)t * G3 + j;
        st_agent(gp,           dr + psum[0][j] + b0);
        st_agent(gp + HID,     dz + psum[1][j] + b1);
        st_agent(gp + 2 * HID, dn + psum[2][j] + b2);
      }
      done++;
      if ((done & 1) == 0) {                  // publish every 2 processed
        __syncthreads();
        if (tid == 0) st_ctr(&ctr[1 + f], t + 1);
      }
    }
    __syncthreads();
    if (tid == 0) st_ctr(&ctr[1 + f], T);
  }
}

// ---------------------------------------------------------------------------
// Attention per-node dots: a_s[n,h] = feat[n,h,:].att_src[h,:]  (same for dst)
// ---------------------------------------------------------------------------
__global__ void att_dots(const float* __restrict__ feat,
                         const float* __restrict__ att_src,
                         const float* __restrict__ att_dst,
                         float* __restrict__ a_s, float* __restrict__ a_d,
                         int heads, int C) {
  const int n = blockIdx.x;
  const int h = threadIdx.x >> 6;
  const int lane = threadIdx.x & 63;
  float ss = 0.f, dd = 0.f;
  const float* f = feat + (size_t)n * heads * C + h * C;
  for (int c = lane; c < C; c += 64) {
    const float v = f[c];
    ss = fmaf(v, att_src[h * C + c], ss);
    dd = fmaf(v, att_dst[h * C + c], dd);
  }
#pragma unroll
  for (int o = 32; o > 0; o >>= 1) {
    ss += __shfl_down(ss, o);
    dd += __shfl_down(dd, o);
  }
  if (lane == 0) { a_s[n * heads + h] = ss; a_d[n * heads + h] = dd; }
}

// ---------------------------------------------------------------------------
// CSR build (edge_index arrives as int32: ei[0..E) = src, ei[E..2E) = dst)
// ---------------------------------------------------------------------------
__global__ void edge_count(const int* __restrict__ ei, int* __restrict__ cnt, int E) {
  const int e = blockIdx.x * 256 + threadIdx.x;
  if (e < E) atomicAdd(&cnt[ei[E + e]], 1);
}

__global__ __launch_bounds__(1024) void prefix_scan(const int* __restrict__ cnt,
                                                    int* __restrict__ offs,
                                                    int* __restrict__ cursor, int N) {
  __shared__ int buf[1024];
  __shared__ int carry;
  const int tid = threadIdx.x;
  if (tid == 0) carry = 0;
  __syncthreads();
  for (int base = 0; base < N; base += 1024) {
    const int i = base + tid;
    const int v = (i < N) ? cnt[i] : 0;
    buf[tid] = v;
    __syncthreads();
    for (int d = 1; d < 1024; d <<= 1) {
      int t = 0;
      if (tid >= d) t = buf[tid - d];
      __syncthreads();
      buf[tid] += t;
      __syncthreads();
    }
    const int incl = buf[tid] + carry;
    if (i < N) { offs[i] = incl - v; cursor[i] = incl - v; }
    __syncthreads();
    if (tid == 1023) carry = incl;
    __syncthreads();
  }
  if (tid == 0) offs[N] = carry;
}

__global__ void edge_fill(const int* __restrict__ ei, int* __restrict__ cursor,
                          int* __restrict__ csr, int E) {
  const int e = blockIdx.x * 256 + threadIdx.x;
  if (e < E) {
    const int d = ei[E + e];
    const int s = ei[e];
    const int pos = atomicAdd(&cursor[d], 1);
    csr[pos] = s;
  }
}

// ---------------------------------------------------------------------------
// GAT softmax-aggregation.  One block per dst node; blockDim = heads<<cshift.
// ---------------------------------------------------------------------------
__global__ void gat_agg(const float* __restrict__ feat,
                        const float* __restrict__ a_s, const float* __restrict__ a_d,
                        const int* __restrict__ offs, const int* __restrict__ csr,
                        const float* __restrict__ bias, float* __restrict__ out,
                        int heads, int cshift, int do_relu) {
  const int n = blockIdx.x;
  const int t = threadIdx.x;
  const int HC = blockDim.x;
  const int h = t >> cshift;
  const int beg = offs[n], end = offs[n + 1];
  const float ad = a_d[n * heads + h];
  const float self_e = leakyf_(a_s[n * heads + h] + ad);
  float m = self_e;
  for (int i = beg; i < end; i++) {
    const int s = csr[i];
    m = fmaxf(m, leakyf_(a_s[s * heads + h] + ad));
  }
  float den = expf(self_e - m);
  float acc = den * feat[(size_t)n * HC + t];
  for (int i = beg; i < end; i++) {
    const int s = csr[i];
    const float wgt = expf(leakyf_(a_s[s * heads + h] + ad) - m);
    den += wgt;
    acc = fmaf(wgt, feat[(size_t)s * HC + t], acc);
  }
  float o = acc / den + bias[t];
  if (do_relu) o = fmaxf(o, 0.f);
  out[(size_t)n * HC + t] = o;
}

// ---------------------------------------------------------------------------
extern "C" void kernel_launch(void* const* d_in, const int* in_sizes, int n_in,
                              void* d_out, int out_size, void* d_ws, size_t ws_size,
                              hipStream_t stream) {
  const float* x        = (const float*)d_in[0];
  const int*   ei       = (const int*)d_in[1];   // int64 inputs arrive as int32
  const float* w_ih0    = (const float*)d_in[2];
  const float* w_hh0    = (const float*)d_in[3];
  const float* b_ih0    = (const float*)d_in[4];
  const float* b_hh0    = (const float*)d_in[5];
  const float* w_ih1    = (const float*)d_in[6];
  const float* w_hh1    = (const float*)d_in[7];
  const float* b_ih1    = (const float*)d_in[8];
  const float* b_hh1    = (const float*)d_in[9];
  const float* W1       = (const float*)d_in[10];
  const float* att_src1 = (const float*)d_in[11];
  const float* att_dst1 = (const float*)d_in[12];
  const float* bias1    = (const float*)d_in[13];
  const float* W2       = (const float*)d_in[14];
  const float* att_src2 = (const float*)d_in[15];
  const float* att_dst2 = (const float*)d_in[16];
  const float* bias2    = (const float*)d_in[17];
  float* out = (float*)d_out;

  const int N = NN_;
  const int E = in_sizes[1] / 2;

  // ---- workspace layout with overlays (peak ~54 MB) ----
  float* f    = (float*)d_ws;
  float* gi   = f;                         // region A (gi0; dead after scan)
  float* hmm1 = f;                         // = A, reused for GAT1 features
  float* h1   = f + (size_t)N * HC1;                    // B
  float* g1o  = h1 + (size_t)N * HID;                   // C (post-scan)
  float* hmm2 = g1o + (size_t)N * HC1;                  // D
  float* as1  = hmm2 + (size_t)N * OUTD;
  float* ad1  = as1 + (size_t)N * 4;
  float* as2  = ad1 + (size_t)N * 4;
  float* ad2  = as2 + (size_t)N;
  int* cnt    = (int*)(ad2 + (size_t)N);
  int* offs   = cnt + N;        // N+1
  int* cursor = offs + (N + 1);
  int* csr    = cursor + N;     // E
  int* ctr    = csr + E;        // 3 ints: prog0, pf0, pf1
  // scan-time streams overlay region C (g1o): N*64 uints (fp16 h0) + N*G3
  // floats (gi1) = N*448 float-slots <= N*HC1 ✓
  unsigned* h0_st16 = (unsigned*)g1o;
  float*    gi1_st  = g1o + (size_t)N * 64;

  const int mblocks = (N + 63) / 64;

  // GRU: gi0 GEMM, zero counters, then 4-CU pipelined two-layer scan
  gemm_k<true><<<dim3(mblocks, G3 / 64), 256, 0, stream>>>(x, w_ih0, b_ih0, gi, N, G3, IND);
  hipMemsetAsync(ctr, 0, 3 * sizeof(int), stream);
  gru_pipe<<<4, 256, 0, stream>>>(gi, w_hh0, b_hh0, w_ih1, b_ih1, w_hh1, b_hh1,
                                  h0_st16, gi1_st, ctr, h1, N);

  // CSR by dst (shared by both GAT layers)
  hipMemsetAsync(cnt, 0, (size_t)N * sizeof(int), stream);
  edge_count<<<(E + 255) / 256, 256, 0, stream>>>(ei, cnt, E);
  prefix_scan<<<1, 1024, 0, stream>>>(cnt, offs, cursor, N);
  edge_fill<<<(E + 255) / 256, 256, 0, stream>>>(ei, cursor, csr, E);

  // GAT layer 1
  gemm_k<false><<<dim3(mblocks, HC1 / 64), 256, 0, stream>>>(h1, W1, nullptr, hmm1, N, HC1, HID);
  att_dots<<<N, 4 * 64, 0, stream>>>(hmm1, att_src1, att_dst1, as1, ad1, 4, HID);
  gat_agg<<<N, HC1, 0, stream>>>(hmm1, as1, ad1, offs, csr, bias1, g1o, 4, 7, 1);

  // GAT layer 2
  gemm_k<false><<<dim3(mblocks, OUTD / 64), 256, 0, stream>>>(g1o, W2, nullptr, hmm2, N, OUTD, HC1);
  att_dots<<<N, 1 * 64, 0, stream>>>(hmm2, att_src2, att_dst2, as2, ad2, 1, OUTD);
  gat_agg<<<N, OUTD, 0, stream>>>(hmm2, as2, ad2, offs, csr, bias2, out, 1, 6, 0);
}

// Round 11
// 6313.119 us; speedup vs baseline: 2.2276x; 1.0952x over previous
//
#include <hip/hip_runtime.h>
#include <math.h>

#define NN_  10000
#define NE_  320000
#define IND  64
#define HID  128
#define G3   384   // 3*HID
#define HC1  512   // 4 heads * 128
#define OUTD 64

typedef _Float16 h2f __attribute__((ext_vector_type(2)));
union UH4 { uint4 u; h2f h[4]; };

__device__ __forceinline__ float leakyf_(float x){ return x>0.f ? x : 0.2f*x; }
__device__ __forceinline__ float fsig_(float x){ return 1.f/(1.f+__expf(-x)); }
__device__ __forceinline__ float ftanh_(float x){ float e=__expf(2.f*x); return 1.f-2.f/(e+1.f); }

// LDS-only barrier: waits LDS ops, does NOT drain vmcnt.
#define BARRIER_LDS() asm volatile("s_waitcnt lgkmcnt(0)\n\ts_barrier" ::: "memory")
#define WAIT_VM0()    asm volatile("s_waitcnt vmcnt(0)" ::: "memory")

// agent-scope (device) atomic helpers for cross-block streams
__device__ __forceinline__ float ld_agent(const float* p) {
  return __hip_atomic_load(p, __ATOMIC_RELAXED, __HIP_MEMORY_SCOPE_AGENT);
}
__device__ __forceinline__ void st_agent(float* p, float v) {
  __hip_atomic_store(p, v, __ATOMIC_RELAXED, __HIP_MEMORY_SCOPE_AGENT);
}
__device__ __forceinline__ unsigned ld_agent_u32(const unsigned* p) {
  return __hip_atomic_load(p, __ATOMIC_RELAXED, __HIP_MEMORY_SCOPE_AGENT);
}
__device__ __forceinline__ void st_agent_u32(unsigned* p, unsigned v) {
  __hip_atomic_store(p, v, __ATOMIC_RELAXED, __HIP_MEMORY_SCOPE_AGENT);
}
__device__ __forceinline__ int ld_ctr(const int* p) {
  return __hip_atomic_load(p, __ATOMIC_ACQUIRE, __HIP_MEMORY_SCOPE_AGENT);
}
__device__ __forceinline__ void st_ctr(int* p, int v) {
  __hip_atomic_store(p, v, __ATOMIC_RELEASE, __HIP_MEMORY_SCOPE_AGENT);
}

// ---------------------------------------------------------------------------
// Generic tiled fp32 GEMM.  C[m,n] = sum_k A[m,k] * (TB ? B[n,k] : B[k,n]) + bias[n]
// ---------------------------------------------------------------------------
template<bool TB>
__global__ __launch_bounds__(256) void gemm_k(const float* __restrict__ A,
                                              const float* __restrict__ B,
                                              const float* __restrict__ bias,
                                              float* __restrict__ C,
                                              int M, int N, int K) {
  __shared__ float As[16][65];
  __shared__ float Bs[16][65];
  const int bm = blockIdx.x * 64, bn = blockIdx.y * 64;
  const int tid = threadIdx.x;
  const int tm = (tid >> 4) << 2, tn = (tid & 15) << 2;
  float acc[4][4] = {};
  const int row = tid & 63, kq = (tid >> 6) << 2;
  for (int k0 = 0; k0 < K; k0 += 16) {
    float4 av = make_float4(0.f, 0.f, 0.f, 0.f);
    const int m = bm + row;
    if (m < M) av = *(const float4*)(A + (size_t)m * K + k0 + kq);
    As[kq + 0][row] = av.x; As[kq + 1][row] = av.y;
    As[kq + 2][row] = av.z; As[kq + 3][row] = av.w;
    if (TB) {
      float4 bv = *(const float4*)(B + (size_t)(bn + row) * K + k0 + kq);
      Bs[kq + 0][row] = bv.x; Bs[kq + 1][row] = bv.y;
      Bs[kq + 2][row] = bv.z; Bs[kq + 3][row] = bv.w;
    } else {
      const int kr = tid >> 4, nq = (tid & 15) << 2;
      float4 bv = *(const float4*)(B + (size_t)(k0 + kr) * N + bn + nq);
      Bs[kr][nq + 0] = bv.x; Bs[kr][nq + 1] = bv.y;
      Bs[kr][nq + 2] = bv.z; Bs[kr][nq + 3] = bv.w;
    }
    __syncthreads();
#pragma unroll
    for (int kk = 0; kk < 16; kk++) {
      float a[4], b[4];
#pragma unroll
      for (int i = 0; i < 4; i++) a[i] = As[kk][tm + i];
#pragma unroll
      for (int j = 0; j < 4; j++) b[j] = Bs[kk][tn + j];
#pragma unroll
      for (int i = 0; i < 4; i++)
#pragma unroll
        for (int j = 0; j < 4; j++) acc[i][j] = fmaf(a[i], b[j], acc[i][j]);
    }
    __syncthreads();
  }
#pragma unroll
  for (int i = 0; i < 4; i++) {
    const int m = bm + tm + i;
    if (m < M) {
#pragma unroll
      for (int j = 0; j < 4; j++) {
        const int n = bn + tn + j;
        float v = acc[i][j];
        if (bias) v += bias[n];
        C[(size_t)m * N + n] = v;
      }
    }
  }
}

// ---------------------------------------------------------------------------
// Pipelined two-layer GRU across 4 CUs.  4 blocks x 256 threads:
//  block 0: layer-0 scan -> fp16 h0 stream + progress ctr every 8 steps
//  blocks 1,2: gi1 factories (parity-split), BATCHED: poll once per 4 items,
//              prefetch all 4 h0 vectors to registers, publish per batch
//  block 3: layer-1 scan consuming gi1; polls ctrs once per 32 steps
// gi prefetch: unroll-by-4 with FOUR independent register sets, reloaded
// after consumption -> s_waitcnt lands ~4 steps after issue (>5000 cyc
// cover, hides any cross-XCD LLC latency).
// ---------------------------------------------------------------------------
__global__ __launch_bounds__(256, 1) void gru_pipe(const float* __restrict__ gi0,
                                                   const float* __restrict__ w_hh0,
                                                   const float* __restrict__ b_hh0,
                                                   const float* __restrict__ w_ih1,
                                                   const float* __restrict__ b_ih1,
                                                   const float* __restrict__ w_hh1,
                                                   const float* __restrict__ b_hh1,
                                                   unsigned* h0_st16, float* gi1_st,
                                                   int* ctr,           // [0]=prog0 [1]=pf0 [2]=pf1
                                                   float* __restrict__ h1_out,
                                                   int T) {
  __shared__ _Float16 hbuf[2][HID];
  __shared__ float psum[3][HID];

  const int bid   = blockIdx.x;
  const int tid   = threadIdx.x;
  const int khalf = (tid >> 6) & 1;
  const int j     = (tid & 63) | ((tid >> 7) << 6);
  const int kbase = khalf * 64;

  const float* wsrc = (bid == 0) ? w_hh0 : (bid == 3 ? w_hh1 : w_ih1);
  const float* bsrc = (bid == 0) ? b_hh0 : (bid == 3 ? b_hh1 : b_ih1);

  // load + convert this thread's half-rows of the 3 gates to packed fp16
  h2f wr[32], wz[32], wn[32];
#pragma unroll
  for (int i = 0; i < 16; i++) {
    float4 a = *(const float4*)(wsrc + (size_t)j * HID + kbase + i * 4);
    wr[2 * i]     = h2f{(_Float16)a.x, (_Float16)a.y};
    wr[2 * i + 1] = h2f{(_Float16)a.z, (_Float16)a.w};
  }
#pragma unroll
  for (int i = 0; i < 16; i++) {
    float4 a = *(const float4*)(wsrc + (size_t)(j + HID) * HID + kbase + i * 4);
    wz[2 * i]     = h2f{(_Float16)a.x, (_Float16)a.y};
    wz[2 * i + 1] = h2f{(_Float16)a.z, (_Float16)a.w};
  }
#pragma unroll
  for (int i = 0; i < 16; i++) {
    float4 a = *(const float4*)(wsrc + (size_t)(j + 2 * HID) * HID + kbase + i * 4);
    wn[2 * i]     = h2f{(_Float16)a.x, (_Float16)a.y};
    wn[2 * i + 1] = h2f{(_Float16)a.z, (_Float16)a.w};
  }
  const float b0 = bsrc[j];
  const float b1 = bsrc[j + HID];
  const float b2 = bsrc[j + 2 * HID];

  // dot over this thread's K-half from an LDS fp16 vector at 'hp16'
  auto dot_half = [&](const _Float16* hp16, float& r, float& z, float& n) {
    const uint4* hp = (const uint4*)(hp16 + kbase);
    float ar0 = 0.f, ar1 = 0.f, az0 = 0.f, az1 = 0.f, an0 = 0.f, an1 = 0.f;
#pragma unroll
    for (int c = 0; c < 2; c++) {
      uint4 hv[4];
#pragma unroll
      for (int i = 0; i < 4; i++) hv[i] = hp[c * 4 + i];
#pragma unroll
      for (int i = 0; i < 4; i++) {
        UH4 v; v.u = hv[i];
#pragma unroll
        for (int q = 0; q < 4; q++) {
          const int k = c * 16 + i * 4 + q;
          const h2f hh = v.h[q];
          if (k & 1) {
            ar1 = __builtin_amdgcn_fdot2(wr[k], hh, ar1, false);
            az1 = __builtin_amdgcn_fdot2(wz[k], hh, az1, false);
            an1 = __builtin_amdgcn_fdot2(wn[k], hh, an1, false);
          } else {
            ar0 = __builtin_amdgcn_fdot2(wr[k], hh, ar0, false);
            az0 = __builtin_amdgcn_fdot2(wz[k], hh, az0, false);
            an0 = __builtin_amdgcn_fdot2(wn[k], hh, an0, false);
          }
        }
      }
    }
    r = ar0 + ar1; z = az0 + az1; n = an0 + an1;
  };

  if (bid == 0 || bid == 3) {
    // ---------------- scan roles (bid0 = layer-0, bid3 = layer-1) -----------
    const float* gsrc = (bid == 0) ? gi0 : gi1_st;
    float hcur = 0.f;
    if (khalf == 0) hbuf[0][j] = (_Float16)0.f;
    BARRIER_LDS();

    if (bid == 3 && tid == 0) {            // ensure gi1[0..3] published
      while (ld_ctr(&ctr[1]) < 4) {}
      while (ld_ctr(&ctr[2]) < 4) {}
    }
    if (bid == 3) __syncthreads();

    // four independent prefetch register sets (t mod 4 = 0,1,2,3)
    float gxA, gyA, gzA, gxB, gyB, gzB, gxC, gyC, gzC, gxD, gyD, gzD;
    if (khalf == 0) {
      const float* gp = gsrc + j;
      gxA = gp[0]; gyA = gp[HID]; gzA = gp[2 * HID];
      gp = gsrc + (size_t)1 * G3 + j;
      gxB = gp[0]; gyB = gp[HID]; gzB = gp[2 * HID];
      gp = gsrc + (size_t)2 * G3 + j;
      gxC = gp[0]; gyC = gp[HID]; gzC = gp[2 * HID];
      gp = gsrc + (size_t)3 * G3 + j;
      gxD = gp[0]; gyD = gp[HID]; gzD = gp[2 * HID];
    }

    auto substep = [&](int tc, int pin, float& gx, float& gy, float& gz) {
      float dr, dz, dn;
      dot_half(&hbuf[pin][0], dr, dz, dn);
      if (khalf == 1) { psum[0][j] = dr; psum[1][j] = dz; psum[2][j] = dn; }
      BARRIER_LDS();
      if (khalf == 0) {
        const float r = fsig_(gx + b0 + dr + psum[0][j]);
        const float z = fsig_(gy + b1 + dz + psum[1][j]);
        const float n = ftanh_(gz + r * (b2 + dn + psum[2][j]));
        hcur = (1.f - z) * n + z * hcur;
        hbuf[pin ^ 1][j] = (_Float16)hcur;
        if (bid == 3) h1_out[(size_t)tc * HID + j] = hcur;
        // reload this set for tc+4 (consumed 4 sub-steps later)
        const int tp = (tc + 4 < T) ? (tc + 4) : 0;
        const float* gp = gsrc + (size_t)tp * G3 + j;
        gx = gp[0]; gy = gp[HID]; gz = gp[2 * HID];
      }
      // consumer: poll once per 32 steps, deep margin (amortized LLC spin)
      if (bid == 3 && tid == 0 && (tc & 31) == 0) {
        int need = tc + 36; if (need > T) need = T;
        while (ld_ctr(&ctr[1]) < need) {}
        while (ld_ctr(&ctr[2]) < need) {}
      }
      BARRIER_LDS();
      // producer: wave 1 (stores only in its vmcnt) exports fp16 h0[tc]
      if (bid == 0 && tid >= 64 && tid < 128) {
        const int idx = tid - 64;
        unsigned v = *(const unsigned*)&hbuf[pin ^ 1][2 * idx];
        st_agent_u32(&h0_st16[(size_t)tc * 64 + idx], v);
        if ((tc & 7) == 7) {
          WAIT_VM0();                        // drains only wave-1 stores
          if (tid == 64) st_ctr(&ctr[0], tc + 1);
        }
      }
    };

    for (int t = 0; t < T; t += 4) {
      substep(t,     0, gxA, gyA, gzA);
      substep(t + 1, 1, gxB, gyB, gzB);
      substep(t + 2, 0, gxC, gyC, gzC);
      substep(t + 3, 1, gxD, gyD, gzD);
    }
    if (bid == 0 && tid >= 64 && tid < 128) {  // final publish
      WAIT_VM0();
      if (tid == 64) st_ctr(&ctr[0], T);
    }
  } else {
    // ---------------- factory roles (gi1 for parity f), BATCHED -------------
    const int f = bid - 1;                    // 0 or 1
    _Float16* hstage = &hbuf[0][0];           // single staging buffer
    for (int t0 = f; t0 < T; t0 += 8) {       // batch: t0, t0+2, t0+4, t0+6
      if (tid == 0) {
        int need = t0 + 7; if (need > T) need = T;
        while (ld_ctr(&ctr[0]) < need) {}
      }
      __syncthreads();
      // prefetch all 4 h0 vectors for this batch into registers
      unsigned hv0 = 0, hv1 = 0, hv2 = 0, hv3 = 0;
      if (tid < 64) {
        hv0 = ld_agent_u32(&h0_st16[(size_t)t0 * 64 + tid]);
        if (t0 + 2 < T) hv1 = ld_agent_u32(&h0_st16[(size_t)(t0 + 2) * 64 + tid]);
        if (t0 + 4 < T) hv2 = ld_agent_u32(&h0_st16[(size_t)(t0 + 4) * 64 + tid]);
        if (t0 + 6 < T) hv3 = ld_agent_u32(&h0_st16[(size_t)(t0 + 6) * 64 + tid]);
      }
#pragma unroll
      for (int k = 0; k < 4; k++) {
        const int t = t0 + 2 * k;
        if (t >= T) break;
        if (tid < 64) {
          const unsigned hv = (k == 0) ? hv0 : (k == 1) ? hv1 : (k == 2) ? hv2 : hv3;
          ((unsigned*)hstage)[tid] = hv;
        }
        BARRIER_LDS();
        float dr, dz, dn;
        dot_half(hstage, dr, dz, dn);
        if (khalf == 1) { psum[0][j] = dr; psum[1][j] = dz; psum[2][j] = dn; }
        BARRIER_LDS();
        if (khalf == 0) {
          float* gp = gi1_st + (size_t)t * G3 + j;
          st_agent(gp,           dr + psum[0][j] + b0);
          st_agent(gp + HID,     dz + psum[1][j] + b1);
          st_agent(gp + 2 * HID, dn + psum[2][j] + b2);
        }
      }
      __syncthreads();                        // drain gi1 stores (all waves)
      if (tid == 0) {
        int pub = t0 + 8; if (pub > T) pub = T;
        st_ctr(&ctr[1 + f], pub);
      }
    }
    __syncthreads();
    if (tid == 0) st_ctr(&ctr[1 + f], T);
  }
}

// ---------------------------------------------------------------------------
// Attention per-node dots: a_s[n,h] = feat[n,h,:].att_src[h,:]  (same for dst)
// ---------------------------------------------------------------------------
__global__ void att_dots(const float* __restrict__ feat,
                         const float* __restrict__ att_src,
                         const float* __restrict__ att_dst,
                         float* __restrict__ a_s, float* __restrict__ a_d,
                         int heads, int C) {
  const int n = blockIdx.x;
  const int h = threadIdx.x >> 6;
  const int lane = threadIdx.x & 63;
  float ss = 0.f, dd = 0.f;
  const float* f = feat + (size_t)n * heads * C + h * C;
  for (int c = lane; c < C; c += 64) {
    const float v = f[c];
    ss = fmaf(v, att_src[h * C + c], ss);
    dd = fmaf(v, att_dst[h * C + c], dd);
  }
#pragma unroll
  for (int o = 32; o > 0; o >>= 1) {
    ss += __shfl_down(ss, o);
    dd += __shfl_down(dd, o);
  }
  if (lane == 0) { a_s[n * heads + h] = ss; a_d[n * heads + h] = dd; }
}

// ---------------------------------------------------------------------------
// CSR build (edge_index arrives as int32: ei[0..E) = src, ei[E..2E) = dst)
// ---------------------------------------------------------------------------
__global__ void edge_count(const int* __restrict__ ei, int* __restrict__ cnt, int E) {
  const int e = blockIdx.x * 256 + threadIdx.x;
  if (e < E) atomicAdd(&cnt[ei[E + e]], 1);
}

__global__ __launch_bounds__(1024) void prefix_scan(const int* __restrict__ cnt,
                                                    int* __restrict__ offs,
                                                    int* __restrict__ cursor, int N) {
  __shared__ int buf[1024];
  __shared__ int carry;
  const int tid = threadIdx.x;
  if (tid == 0) carry = 0;
  __syncthreads();
  for (int base = 0; base < N; base += 1024) {
    const int i = base + tid;
    const int v = (i < N) ? cnt[i] : 0;
    buf[tid] = v;
    __syncthreads();
    for (int d = 1; d < 1024; d <<= 1) {
      int t = 0;
      if (tid >= d) t = buf[tid - d];
      __syncthreads();
      buf[tid] += t;
      __syncthreads();
    }
    const int incl = buf[tid] + carry;
    if (i < N) { offs[i] = incl - v; cursor[i] = incl - v; }
    __syncthreads();
    if (tid == 1023) carry = incl;
    __syncthreads();
  }
  if (tid == 0) offs[N] = carry;
}

__global__ void edge_fill(const int* __restrict__ ei, int* __restrict__ cursor,
                          int* __restrict__ csr, int E) {
  const int e = blockIdx.x * 256 + threadIdx.x;
  if (e < E) {
    const int d = ei[E + e];
    const int s = ei[e];
    const int pos = atomicAdd(&cursor[d], 1);
    csr[pos] = s;
  }
}

// ---------------------------------------------------------------------------
// GAT softmax-aggregation.  One block per dst node; blockDim = heads<<cshift.
// ---------------------------------------------------------------------------
__global__ void gat_agg(const float* __restrict__ feat,
                        const float* __restrict__ a_s, const float* __restrict__ a_d,
                        const int* __restrict__ offs, const int* __restrict__ csr,
                        const float* __restrict__ bias, float* __restrict__ out,
                        int heads, int cshift, int do_relu) {
  const int n = blockIdx.x;
  const int t = threadIdx.x;
  const int HC = blockDim.x;
  const int h = t >> cshift;
  const int beg = offs[n], end = offs[n + 1];
  const float ad = a_d[n * heads + h];
  const float self_e = leakyf_(a_s[n * heads + h] + ad);
  float m = self_e;
  for (int i = beg; i < end; i++) {
    const int s = csr[i];
    m = fmaxf(m, leakyf_(a_s[s * heads + h] + ad));
  }
  float den = expf(self_e - m);
  float acc = den * feat[(size_t)n * HC + t];
  for (int i = beg; i < end; i++) {
    const int s = csr[i];
    const float wgt = expf(leakyf_(a_s[s * heads + h] + ad) - m);
    den += wgt;
    acc = fmaf(wgt, feat[(size_t)s * HC + t], acc);
  }
  float o = acc / den + bias[t];
  if (do_relu) o = fmaxf(o, 0.f);
  out[(size_t)n * HC + t] = o;
}

// ---------------------------------------------------------------------------
extern "C" void kernel_launch(void* const* d_in, const int* in_sizes, int n_in,
                              void* d_out, int out_size, void* d_ws, size_t ws_size,
                              hipStream_t stream) {
  const float* x        = (const float*)d_in[0];
  const int*   ei       = (const int*)d_in[1];   // int64 inputs arrive as int32
  const float* w_ih0    = (const float*)d_in[2];
  const float* w_hh0    = (const float*)d_in[3];
  const float* b_ih0    = (const float*)d_in[4];
  const float* b_hh0    = (const float*)d_in[5];
  const float* w_ih1    = (const float*)d_in[6];
  const float* w_hh1    = (const float*)d_in[7];
  const float* b_ih1    = (const float*)d_in[8];
  const float* b_hh1    = (const float*)d_in[9];
  const float* W1       = (const float*)d_in[10];
  const float* att_src1 = (const float*)d_in[11];
  const float* att_dst1 = (const float*)d_in[12];
  const float* bias1    = (const float*)d_in[13];
  const float* W2       = (const float*)d_in[14];
  const float* att_src2 = (const float*)d_in[15];
  const float* att_dst2 = (const float*)d_in[16];
  const float* bias2    = (const float*)d_in[17];
  float* out = (float*)d_out;

  const int N = NN_;
  const int E = in_sizes[1] / 2;

  // ---- workspace layout with overlays (peak ~54 MB) ----
  float* f    = (float*)d_ws;
  float* gi   = f;                         // region A (gi0; dead after scan)
  float* hmm1 = f;                         // = A, reused for GAT1 features
  float* h1   = f + (size_t)N * HC1;                    // B
  float* g1o  = h1 + (size_t)N * HID;                   // C (post-scan)
  float* hmm2 = g1o + (size_t)N * HC1;                  // D
  float* as1  = hmm2 + (size_t)N * OUTD;
  float* ad1  = as1 + (size_t)N * 4;
  float* as2  = ad1 + (size_t)N * 4;
  float* ad2  = as2 + (size_t)N;
  int* cnt    = (int*)(ad2 + (size_t)N);
  int* offs   = cnt + N;        // N+1
  int* cursor = offs + (N + 1);
  int* csr    = cursor + N;     // E
  int* ctr    = csr + E;        // 3 ints: prog0, pf0, pf1
  // scan-time streams overlay region C (g1o): N*64 uints (fp16 h0) + N*G3
  // floats (gi1) = N*448 float-slots <= N*HC1 ✓
  unsigned* h0_st16 = (unsigned*)g1o;
  float*    gi1_st  = g1o + (size_t)N * 64;

  const int mblocks = (N + 63) / 64;

  // GRU: gi0 GEMM, zero counters, then 4-CU pipelined two-layer scan
  gemm_k<true><<<dim3(mblocks, G3 / 64), 256, 0, stream>>>(x, w_ih0, b_ih0, gi, N, G3, IND);
  hipMemsetAsync(ctr, 0, 3 * sizeof(int), stream);
  gru_pipe<<<4, 256, 0, stream>>>(gi, w_hh0, b_hh0, w_ih1, b_ih1, w_hh1, b_hh1,
                                  h0_st16, gi1_st, ctr, h1, N);

  // CSR by dst (shared by both GAT layers)
  hipMemsetAsync(cnt, 0, (size_t)N * sizeof(int), stream);
  edge_count<<<(E + 255) / 256, 256, 0, stream>>>(ei, cnt, E);
  prefix_scan<<<1, 1024, 0, stream>>>(cnt, offs, cursor, N);
  edge_fill<<<(E + 255) / 256, 256, 0, stream>>>(ei, cursor, csr, E);

  // GAT layer 1
  gemm_k<false><<<dim3(mblocks, HC1 / 64), 256, 0, stream>>>(h1, W1, nullptr, hmm1, N, HC1, HID);
  att_dots<<<N, 4 * 64, 0, stream>>>(hmm1, att_src1, att_dst1, as1, ad1, 4, HID);
  gat_agg<<<N, HC1, 0, stream>>>(hmm1, as1, ad1, offs, csr, bias1, g1o, 4, 7, 1);

  // GAT layer 2
  gemm_k<false><<<dim3(mblocks, OUTD / 64), 256, 0, stream>>>(g1o, W2, nullptr, hmm2, N, OUTD, HC1);
  att_dots<<<N, 1 * 64, 0, stream>>>(hmm2, att_src2, att_dst2, as2, ad2, 1, OUTD);
  gat_agg<<<N, OUTD, 0, stream>>>(hmm2, as2, ad2, offs, csr, bias2, out, 1, 6, 0);
}